// Round 16
// baseline (124.486 us; speedup 1.0000x reference)
//
#include <hip/hip_runtime.h>
#include <hip/hip_fp16.h>
#include <math.h>

constexpr int B = 32;
constexpr int NN = 2048;   // nodes
constexpr int E = 65536;   // edges
constexpr float SLOPE = 0.01f;

typedef __attribute__((ext_vector_type(8))) _Float16 f16x8;
typedef __attribute__((ext_vector_type(4))) float f32x4;

__device__ __forceinline__ float lrelu(float x) { return fmaxf(x, SLOPE * x); }
__device__ __forceinline__ int imin(int a, int b) { return a < b ? a : b; }
__device__ __forceinline__ int imax(int a, int b) { return a > b ? a : b; }

__device__ __forceinline__ unsigned int cvtpk(float lo, float hi) {
    unsigned int r;
    asm("v_cvt_pk_bf16_f32 %0, %1, %2" : "=v"(r) : "v"(lo), "v"(hi));
    return r;
}
__device__ __forceinline__ unsigned int pkrtz(float lo, float hi) {
    unsigned int r;
    asm("v_cvt_pkrtz_f16_f32 %0, %1, %2" : "=v"(r) : "v"(lo), "v"(hi));
    return r;
}
__device__ __forceinline__ unsigned int pk_addrelu(unsigned int a, unsigned int b) {
    unsigned int s, r;
    asm("v_pk_add_f16 %0, %1, %2" : "=v"(s) : "v"(a), "v"(b));
    asm("v_pk_max_f16 %0, %1, %2" : "=v"(r) : "v"(s), "v"(0u));
    return r;
}

__device__ __forceinline__ void unpack_bf16(unsigned int u, float& lo, float& hi) {
    lo = __uint_as_float(u << 16);
    hi = __uint_as_float(u & 0xffff0000u);
}

__device__ __forceinline__ void unpack8(const uint4& u, float f[8]) {
    unpack_bf16(u.x, f[0], f[1]);
    unpack_bf16(u.y, f[2], f[3]);
    unpack_bf16(u.z, f[4], f[5]);
    unpack_bf16(u.w, f[6], f[7]);
}

union UH8 { unsigned int u[4]; uint4 q; f16x8 v; };

// ---- 16-output-half layer helpers (vertex; o0 wave-uniform SGPR) ----
__device__ __forceinline__ void fma_grp16(const float* __restrict__ Wt, int jj, int o0,
                                          const uint4& r, float acc[16]) {
    float x[8]; unpack8(r, x);
    const float* Wp = Wt + jj * 256 + o0;
    #pragma unroll
    for (int jo = 0; jo < 8; ++jo) {
        #pragma unroll
        for (int o = 0; o < 16; ++o) acc[o] += x[jo] * Wp[jo * 32 + o];
    }
}

__device__ __forceinline__ void layerN16(const unsigned short* col, int G, int o0,
                                         const float* __restrict__ Wt, float acc[16]) {
    uint4 cur = *(const uint4*)col;
    #pragma unroll 1
    for (int jj = 0; jj < G; ++jj) {
        uint4 nxt = (jj + 1 < G) ? *(const uint4*)(col + (jj + 1) * 8) : cur;
        fma_grp16(Wt, jj, o0, cur, acc);
        cur = nxt;
    }
}

__device__ __forceinline__ void layer2N16(const unsigned short* col, int G, int o0,
                                          const float* __restrict__ Ws,
                                          const float* __restrict__ Wd,
                                          float a1[16], float a2[16]) {
    uint4 cur = *(const uint4*)col;
    #pragma unroll 1
    for (int jj = 0; jj < G; ++jj) {
        uint4 nxt = (jj + 1 < G) ? *(const uint4*)(col + (jj + 1) * 8) : cur;
        float x[8]; unpack8(cur, x);
        const float* Wps = Ws + jj * 256 + o0;
        const float* Wpd = Wd + jj * 256 + o0;
        #pragma unroll
        for (int jo = 0; jo < 8; ++jo) {
            #pragma unroll
            for (int o = 0; o < 16; ++o) a1[o] += x[jo] * Wps[jo * 32 + o];
            #pragma unroll
            for (int o = 0; o < 16; ++o) a2[o] += x[jo] * Wpd[jo * 32 + o];
        }
        cur = nxt;
    }
}

// ---------------- K1: prep weights + zero cnt/cursor/bacc/dcnt/ticket ----------------
__global__ __launch_bounds__(256) void prep_zero_kernel(
    const float* __restrict__ W1c, const float* __restrict__ W2c,
    const float* __restrict__ W1v, const float* __restrict__ W2v,
    const float* __restrict__ W1e, const float* __restrict__ W2e,
    const float* __restrict__ W1o,
    float* __restrict__ W1cT, float* __restrict__ W2cT,
    float* __restrict__ W1vT, float* __restrict__ W2vT,
    float* __restrict__ W1sT, float* __restrict__ W1dT,
    unsigned short* __restrict__ W2eh, unsigned short* __restrict__ W1oTh,
    int* __restrict__ cnt, int* __restrict__ cursor,
    float* __restrict__ bacc, int* __restrict__ dcnt, int* __restrict__ ticket)
{
    int blk = blockIdx.x;
    if (blk < 8) {
        int i = blk * 256 + threadIdx.x;
        cnt[i] = 0;
        cursor[i] = 0;
        if (blk == 0) {
            if (threadIdx.x < 32) { bacc[threadIdx.x] = 0.f; dcnt[threadIdx.x] = 0; }
            if (threadIdx.x == 32) ticket[0] = 0;
        }
        return;
    }
    int t = (blk - 8) * 256 + threadIdx.x;         // 0..1023
    for (int i = t; i < 32 * 24; i += 1024) W1cT[(i % 24) * 32 + i / 24] = W1c[i];
    for (int i = t; i < 32 * 32; i += 1024) W2cT[(i % 32) * 32 + i / 32] = W2c[i];
    for (int i = t; i < 32 * 64; i += 1024) W1vT[(i % 64) * 32 + i / 64] = W1v[i];
    for (int i = t; i < 32 * 32; i += 1024) W2vT[(i % 32) * 32 + i / 32] = W2v[i];
    for (int i = t; i < 32 * 68; i += 1024) {
        int o = i / 68, j = i % 68;
        if (j < 34) W1sT[j * 32 + o] = W1e[i];
        else        W1dT[(j - 34) * 32 + o] = W1e[i];
    }
    for (int i = t; i < 32 * 32; i += 1024)
        W2eh[i] = __half_as_ushort(__float2half(W2e[i]));
    for (int i = t; i < 512; i += 1024) {
        int o = i >> 4, m = i & 15;
        W1oTh[o * 32 + 2 * m]     = __half_as_ushort(__float2half(W1o[o * 32 + m]));
        W1oTh[o * 32 + 2 * m + 1] = __half_as_ushort(__float2half(W1o[o * 32 + 16 + m]));
    }
}

// ---------------- K2: count + last-block scan ----------------
__global__ __launch_bounds__(1024) void count_scan_kernel(
    const int* __restrict__ edges, int* __restrict__ cnt,
    int* __restrict__ ticket, int* __restrict__ offs)
{
    __shared__ int s[1024];
    __shared__ int lastf;
    int t = threadIdx.x;
    int e = blockIdx.x * 1024 + t;
    atomicAdd(&cnt[edges[E + e]], 1);
    __syncthreads();
    __threadfence();
    if (t == 0) lastf = (atomicAdd(ticket, 1) == 63);
    __syncthreads();
    if (!lastf) return;

    // last block: all counts are device-visible (fence-before-ticket ordering)
    int c0 = atomicAdd(&cnt[2 * t], 0);
    int c1 = atomicAdd(&cnt[2 * t + 1], 0);
    int own = c0 + c1;
    s[t] = own;
    __syncthreads();
    int v = own;
    for (int d = 1; d < 1024; d <<= 1) {
        int add = (t >= d) ? s[t - d] : 0;
        __syncthreads();
        v += add;
        s[t] = v;
        __syncthreads();
    }
    int excl = v - own;
    offs[2 * t] = excl;
    offs[2 * t + 1] = excl + c0;
    if (t == 1023) offs[2048] = v;
}

// ---------------- K3: fill (blocks 0..255) || vertex MLP (blocks 256..767) ----------------
__global__ __launch_bounds__(256) void fill_vertex_kernel(
    const int* __restrict__ edges, const int* __restrict__ offs,
    int* __restrict__ cursor, int* __restrict__ elist,
    const float* __restrict__ vert,
    const float* __restrict__ Wx,  const float* __restrict__ bx,
    const float* __restrict__ Wy,  const float* __restrict__ by,
    const float* __restrict__ Wth, const float* __restrict__ bth,
    const float* __restrict__ b1c, const float* __restrict__ b2c,
    const float* __restrict__ b1v, const float* __restrict__ b2v,
    const float* __restrict__ b1e,
    const float* __restrict__ W1cT, const float* __restrict__ W2cT,
    const float* __restrict__ W1vT, const float* __restrict__ W2vT,
    const float* __restrict__ W1sT, const float* __restrict__ W1dT,
    unsigned int* __restrict__ asrc, unsigned int* __restrict__ adst)
{
    __shared__ unsigned short bufS[128 * 40];   // 10 KB, stride 80 B
    __shared__ unsigned short bufT[128 * 40];   // 10 KB
    __shared__ unsigned short bufC[128 * 72];   // 18.4 KB, stride 144 B

    if (blockIdx.x < 256) {                     // ---- fill branch
        int e = blockIdx.x * 256 + threadIdx.x;
        int d = edges[E + e];
        int p = atomicAdd(&cursor[d], 1);
        elist[offs[d] + p] = edges[e];
        return;
    }

    // ---- vertex branch
    int tid = threadIdx.x;
    int w = tid >> 6, lane = tid & 63;
    int g = w >> 1;
    int h = w & 1;
    int o0 = __builtin_amdgcn_readfirstlane(h << 4);
    int nl = g * 64 + lane;
    int idx = (blockIdx.x - 256) * 128 + nl;
    unsigned short* Sc = bufS + nl * 40;
    unsigned short* Tc = bufT + nl * 40;
    unsigned short* Cc = bufC + nl * 72;

    const float* v = vert + (size_t)idx * 11;
    float qk0 = v[0], qk1 = v[1], qk2 = v[2];
    float q00 = v[3], q01 = v[4], q02 = v[5];
    float qg0 = v[6], qg1 = v[7], qg2 = v[8];
    float col0 = v[9], col1 = v[10];

    for (int cfh = 0; cfh < 2; ++cfh) {
        float a0 = cfh ? qg0 : q00;
        float a1 = cfh ? qg1 : q01;
        float a2 = cfh ? qg2 : q02;
        if (h == 0) {
            #pragma unroll
            for (int i = 0; i < 4; ++i) {
                ((unsigned int*)Sc)[i] = cvtpk(
                    lrelu(qk0 * Wx[4 * i]     + a0 * Wx[4 * i + 1] + bx[2 * i]),
                    lrelu(qk0 * Wx[4 * i + 2] + a0 * Wx[4 * i + 3] + bx[2 * i + 1]));
                ((unsigned int*)Sc)[4 + i] = cvtpk(
                    lrelu(qk1 * Wy[4 * i]     + a1 * Wy[4 * i + 1] + by[2 * i]),
                    lrelu(qk1 * Wy[4 * i + 2] + a1 * Wy[4 * i + 3] + by[2 * i + 1]));
            }
        } else {
            #pragma unroll
            for (int i = 0; i < 4; ++i) {
                ((unsigned int*)Sc)[8 + i] = cvtpk(
                    lrelu(qk2 * Wth[4 * i]     + a2 * Wth[4 * i + 1] + bth[2 * i]),
                    lrelu(qk2 * Wth[4 * i + 2] + a2 * Wth[4 * i + 3] + bth[2 * i + 1]));
            }
        }
        __syncthreads();

        float hh[16];
        #pragma unroll
        for (int o = 0; o < 16; ++o) hh[o] = b1c[o0 + o];
        layerN16(Sc, 3, o0, W1cT, hh);
        #pragma unroll
        for (int q = 0; q < 8; ++q)
            ((unsigned int*)Tc)[h * 8 + q] = cvtpk(lrelu(hh[2 * q]), lrelu(hh[2 * q + 1]));
        __syncthreads();

        float gg[16];
        #pragma unroll
        for (int o = 0; o < 16; ++o) gg[o] = b2c[o0 + o];
        layerN16(Tc, 4, o0, W2cT, gg);
        #pragma unroll
        for (int q = 0; q < 8; ++q)
            ((unsigned int*)Cc)[cfh * 16 + h * 8 + q] =
                cvtpk(lrelu(gg[2 * q]), lrelu(gg[2 * q + 1]));
        __syncthreads();
    }

    float v1[16];
    #pragma unroll
    for (int o = 0; o < 16; ++o) v1[o] = b1v[o0 + o];
    layerN16(Cc, 8, o0, W1vT, v1);
    #pragma unroll
    for (int q = 0; q < 8; ++q)
        ((unsigned int*)Sc)[h * 8 + q] = cvtpk(lrelu(v1[2 * q]), lrelu(v1[2 * q + 1]));
    __syncthreads();

    float v2[16];
    #pragma unroll
    for (int o = 0; o < 16; ++o) v2[o] = b2v[o0 + o];
    layerN16(Sc, 4, o0, W2vT, v2);
    #pragma unroll
    for (int q = 0; q < 8; ++q)
        ((unsigned int*)Tc)[h * 8 + q] = cvtpk(lrelu(v2[2 * q]), lrelu(v2[2 * q + 1]));
    __syncthreads();

    float as[16], ad[16];
    #pragma unroll
    for (int o = 0; o < 16; ++o) { as[o] = 0.f; ad[o] = b1e[o0 + o]; }
    layer2N16(Tc, 4, o0, W1sT, W1dT, as, ad);
    #pragma unroll
    for (int o = 0; o < 16; ++o) {
        as[o] += col0 * W1sT[32 * 32 + o0 + o] + col1 * W1sT[33 * 32 + o0 + o];
        ad[o] += col0 * W1dT[32 * 32 + o0 + o] + col1 * W1dT[33 * 32 + o0 + o];
    }

    unsigned int* ps = asrc + ((size_t)idx << 4) + h * 8;
    unsigned int* pd = adst + ((size_t)idx << 4) + h * 8;
    #pragma unroll
    for (int q = 0; q < 8; ++q) {
        ps[q] = pkrtz(as[2 * q], as[2 * q + 1]);
        pd[q] = pkrtz(ad[2 * q], ad[2 * q + 1]);
    }
}

// ---- one 16-edge chunk step (f16 packed datapath) ----
__device__ __forceinline__ void chunk_step(
    const uint4* __restrict__ abq, const int* __restrict__ elist,
    int e0, int end, int e1, int col, int grp,
    uint4& su_c, int& src_n, const uint4& adr,
    const UH8& Bf0, const UH8& Bf1, float bias0, float bias1,
    float& s0, float& s1)
{
    uint4 su_n = abq[(src_n << 2) | grp];
    int src_n2 = elist[imin(e0 + 32 + col, e1)];

    UH8 A;
    A.u[0] = pk_addrelu(su_c.x, adr.x);
    A.u[1] = pk_addrelu(su_c.y, adr.y);
    A.u[2] = pk_addrelu(su_c.z, adr.z);
    A.u[3] = pk_addrelu(su_c.w, adr.w);
    if ((e0 + col) >= end) {
        A.u[0] = 0; A.u[1] = 0; A.u[2] = 0; A.u[3] = 0;
    }

    f32x4 acc0 = {bias0, bias0, bias0, bias0};
    f32x4 acc1 = {bias1, bias1, bias1, bias1};
    acc0 = __builtin_amdgcn_mfma_f32_16x16x32_f16(A.v, Bf0.v, acc0, 0, 0, 0);
    acc1 = __builtin_amdgcn_mfma_f32_16x16x32_f16(A.v, Bf1.v, acc1, 0, 0, 0);

    #pragma unroll
    for (int r = 0; r < 4; ++r) {
        s0 += lrelu(acc0[r]);
        s1 += lrelu(acc1[r]);
    }
    su_c = su_n;
    src_n = src_n2;
}

// ---------------- K4: edge phase + fused batch reduction/sigmoid ----------------
__global__ __launch_bounds__(512) void edge_final_kernel(
    const unsigned int* __restrict__ asrc, const unsigned int* __restrict__ adst,
    const int* __restrict__ elist, const int* __restrict__ offs,
    const unsigned short* __restrict__ W2eh, const float* __restrict__ b2e,
    const unsigned short* __restrict__ W1oTh, const float* __restrict__ b1o,
    const float* __restrict__ W2o,  const float* __restrict__ b2o,
    const float* __restrict__ Wg,   const float* __restrict__ bg,
    float* __restrict__ bacc, int* __restrict__ dcnt, float* __restrict__ out)
{
    __shared__ unsigned int aggbuf[8 * 16 * 20];    // 10 KB
    int logical = (blockIdx.x & 7) * 64 + (blockIdx.x >> 3);   // XCD swizzle
    int b = logical >> 4;                           // batch
    int seg = logical & 15;                         // dst segment (128 dsts)
    int tid = threadIdx.x;
    int wv = tid >> 6;                              // 0..7
    int lane = tid & 63;
    int col = lane & 15;
    int grp = lane >> 4;

    const uint4* abq = (const uint4*)(asrc + (((size_t)b * NN) << 4));
    unsigned int* wvagg = aggbuf + wv * (16 * 20);

    UH8 Bf0, Bf1;
    Bf0.q = *(const uint4*)(W2eh + col * 32 + grp * 8);
    Bf1.q = *(const uint4*)(W2eh + (col + 16) * 32 + grp * 8);
    UH8 Bo0, Bo1;
    Bo0.q = *(const uint4*)(W1oTh + col * 32 + grp * 8);
    Bo1.q = *(const uint4*)(W1oTh + (col + 16) * 32 + grp * 8);
    float bias0 = b2e[col];
    float bias1 = b2e[col + 16];
    float lb0 = lrelu(bias0);
    float lb1 = lrelu(bias1);
    float b1o_lo = b1o[col];
    float b1o_hi = b1o[col + 16];
    float w2o_lo = W2o[col];
    float w2o_hi = W2o[col + 16];
    float b2oc = b2o[0];
    const unsigned int* adb = adst + (((size_t)b * NN) << 4) + grp * 4;

    int dbase = seg * 128 + wv * 16;                // 16 dsts = 8 pairs per wave
    for (int dp = 0; dp < 8; ++dp) {
        int dA = dbase + 2 * dp;
        int dB = dA + 1;
        int startA = offs[dA];
        int endA = offs[dB];
        int endB = offs[dB + 1];
        int startB = endA;
        int degA = endA - startA;
        int degB = endB - startB;
        int e1A = imax(endA - 1, 0);
        int e1B = imax(endB - 1, 0);

        const uint4 adrA = *(const uint4*)(adb + ((size_t)dA << 4));
        const uint4 adrB = *(const uint4*)(adb + ((size_t)dB << 4));

        int n = imax((degA + 15) >> 4, (degB + 15) >> 4);

        float s0A = 0.f, s1A = 0.f, s0B = 0.f, s1B = 0.f;
        if (n > 0) {
            int srcA = elist[imin(startA + col, e1A)];
            int srcB = elist[imin(startB + col, e1B)];
            uint4 suA = abq[(srcA << 2) | grp];
            uint4 suB = abq[(srcB << 2) | grp];
            int srcnA = elist[imin(startA + 16 + col, e1A)];
            int srcnB = elist[imin(startB + 16 + col, e1B)];

            for (int it = 0; it < n; ++it) {
                int e0A = startA + (it << 4);
                int e0B = startB + (it << 4);
                chunk_step(abq, elist, e0A, endA, e1A, col, grp,
                           suA, srcnA, adrA, Bf0, Bf1, bias0, bias1, s0A, s1A);
                chunk_step(abq, elist, e0B, endB, e1B, col, grp,
                           suB, srcnB, adrB, Bf0, Bf1, bias0, bias1, s0B, s1B);
            }
        }

        s0A += __shfl_xor(s0A, 16); s0A += __shfl_xor(s0A, 32);
        s1A += __shfl_xor(s1A, 16); s1A += __shfl_xor(s1A, 32);
        s0B += __shfl_xor(s0B, 16); s0B += __shfl_xor(s0B, 32);
        s1B += __shfl_xor(s1B, 16); s1B += __shfl_xor(s1B, 32);

        float padA = (float)(16 * n - degA);
        float padB = (float)(16 * n - degB);
        s0A -= padA * lb0; s1A -= padA * lb1;
        s0B -= padB * lb0; s1B -= padB * lb1;

        float invA = 1.f / fmaxf((float)degA, 1.f);
        float invB = 1.f / fmaxf((float)degB, 1.f);
        if (grp == 0) {
            wvagg[(2 * dp) * 20 + col]     = pkrtz(s0A * invA, s1A * invA);
            wvagg[(2 * dp + 1) * 20 + col] = pkrtz(s0B * invB, s1B * invB);
        }
    }

    // batched node MLP (16 dsts) + fused Wg dot
    UH8 Ao;
    Ao.q = *(const uint4*)(wvagg + col * 20 + grp * 4);
    f32x4 acc0 = {b1o_lo, b1o_lo, b1o_lo, b1o_lo};
    f32x4 acc1 = {b1o_hi, b1o_hi, b1o_hi, b1o_hi};
    acc0 = __builtin_amdgcn_mfma_f32_16x16x32_f16(Ao.v, Bo0.v, acc0, 0, 0, 0);
    acc1 = __builtin_amdgcn_mfma_f32_16x16x32_f16(Ao.v, Bo1.v, acc1, 0, 0, 0);

    float p = 0.f;
    #pragma unroll
    for (int r = 0; r < 4; ++r) {                   // dst = dbase + grp*4 + r
        float tt = fmaxf(acc0[r], 0.f) * w2o_lo + fmaxf(acc1[r], 0.f) * w2o_hi;
        tt += __shfl_xor(tt, 1);
        tt += __shfl_xor(tt, 2);
        tt += __shfl_xor(tt, 4);
        tt += __shfl_xor(tt, 8);
        if (col == 0) p += lrelu(tt + b2oc) * Wg[dbase + grp * 4 + r];
    }
    p += __shfl_xor(p, 16);
    p += __shfl_xor(p, 32);
    if (lane == 0) atomicAdd(&bacc[b], p);

    __syncthreads();
    if (tid == 0) {
        __threadfence();
        if (atomicAdd(&dcnt[b], 1) == 15) {         // last of the batch's 16 blocks
            float s = atomicAdd(&bacc[b], 0.f);
            out[b] = 1.f / (1.f + expf(-(s + bg[0])));
        }
    }
}

extern "C" void kernel_launch(void* const* d_in, const int* in_sizes, int n_in,
                              void* d_out, int out_size, void* d_ws, size_t ws_size,
                              hipStream_t stream)
{
    const float* vert = (const float*)d_in[0];
    const int*   edges = (const int*)d_in[1];
    const float* Wx  = (const float*)d_in[2];
    const float* bx  = (const float*)d_in[3];
    const float* Wy  = (const float*)d_in[4];
    const float* by  = (const float*)d_in[5];
    const float* Wth = (const float*)d_in[6];
    const float* bth = (const float*)d_in[7];
    const float* W1c = (const float*)d_in[8];
    const float* b1c = (const float*)d_in[9];
    const float* W2c = (const float*)d_in[10];
    const float* b2c = (const float*)d_in[11];
    const float* W1v = (const float*)d_in[12];
    const float* b1v = (const float*)d_in[13];
    const float* W2v = (const float*)d_in[14];
    const float* b2v = (const float*)d_in[15];
    const float* W1e = (const float*)d_in[16];
    const float* b1e = (const float*)d_in[17];
    const float* W2e = (const float*)d_in[18];
    const float* b2e = (const float*)d_in[19];
    const float* W1o = (const float*)d_in[20];
    const float* b1o = (const float*)d_in[21];
    const float* W2o = (const float*)d_in[22];
    const float* b2o = (const float*)d_in[23];
    const float* Wg  = (const float*)d_in[24];
    const float* bg  = (const float*)d_in[25];
    float* out = (float*)d_out;

    // workspace layout (~8.6 MB, 16B-aligned chunks)
    char* w = (char*)d_ws;
    unsigned int* asrc = (unsigned int*)w; w += (size_t)B * NN * 32 * 2;  // f16 pairs
    unsigned int* adst = (unsigned int*)w; w += (size_t)B * NN * 32 * 2;
    float* W1cT = (float*)w; w += 32 * 24 * 4;
    float* W2cT = (float*)w; w += 32 * 32 * 4;
    float* W1vT = (float*)w; w += 32 * 64 * 4;
    float* W2vT = (float*)w; w += 32 * 32 * 4;
    float* W1sT = (float*)w; w += 34 * 32 * 4;
    float* W1dT = (float*)w; w += 34 * 32 * 4;
    unsigned short* W2eh  = (unsigned short*)w; w += 32 * 32 * 2;
    unsigned short* W1oTh = (unsigned short*)w; w += 32 * 32 * 2;
    int* cnt    = (int*)w;   w += NN * 4;
    int* cursor = (int*)w;   w += NN * 4;
    int* offs   = (int*)w;   w += 2052 * 4;
    int* elist  = (int*)w;   w += E * 4;
    float* bacc = (float*)w; w += 32 * 4;
    int* dcnt   = (int*)w;   w += 32 * 4;
    int* ticket = (int*)w;   w += 4 * 4;

    prep_zero_kernel<<<12, 256, 0, stream>>>(W1c, W2c, W1v, W2v, W1e, W2e, W1o,
                                             W1cT, W2cT, W1vT, W2vT, W1sT, W1dT,
                                             W2eh, W1oTh, cnt, cursor,
                                             bacc, dcnt, ticket);

    count_scan_kernel<<<64, 1024, 0, stream>>>(edges, cnt, ticket, offs);

    fill_vertex_kernel<<<768, 256, 0, stream>>>(
        edges, offs, cursor, elist, vert,
        Wx, bx, Wy, by, Wth, bth, b1c, b2c, b1v, b2v, b1e,
        W1cT, W2cT, W1vT, W2vT, W1sT, W1dT, asrc, adst);

    edge_final_kernel<<<B * 16, 512, 0, stream>>>(
        asrc, adst, elist, offs, W2eh, b2e, W1oTh, b1o, W2o, b2o,
        Wg, bg, bacc, dcnt, out);
}

// Round 18
// 105.065 us; speedup vs baseline: 1.1848x; 1.1848x over previous
//
#include <hip/hip_runtime.h>
#include <hip/hip_fp16.h>
#include <math.h>

constexpr int B = 32;
constexpr int NN = 2048;   // nodes
constexpr int E = 65536;   // edges
constexpr float SLOPE = 0.01f;

typedef __attribute__((ext_vector_type(8))) _Float16 f16x8;
typedef __attribute__((ext_vector_type(4))) float f32x4;

__device__ __forceinline__ float lrelu(float x) { return fmaxf(x, SLOPE * x); }
__device__ __forceinline__ int imin(int a, int b) { return a < b ? a : b; }
__device__ __forceinline__ int imax(int a, int b) { return a > b ? a : b; }

__device__ __forceinline__ unsigned int cvtpk(float lo, float hi) {
    unsigned int r;
    asm("v_cvt_pk_bf16_f32 %0, %1, %2" : "=v"(r) : "v"(lo), "v"(hi));
    return r;
}
__device__ __forceinline__ unsigned int pkrtz(float lo, float hi) {
    unsigned int r;
    asm("v_cvt_pkrtz_f16_f32 %0, %1, %2" : "=v"(r) : "v"(lo), "v"(hi));
    return r;
}
__device__ __forceinline__ unsigned int pk_addrelu(unsigned int a, unsigned int b) {
    unsigned int s, r;
    asm("v_pk_add_f16 %0, %1, %2" : "=v"(s) : "v"(a), "v"(b));
    asm("v_pk_max_f16 %0, %1, %2" : "=v"(r) : "v"(s), "v"(0u));
    return r;
}

__device__ __forceinline__ void unpack_bf16(unsigned int u, float& lo, float& hi) {
    lo = __uint_as_float(u << 16);
    hi = __uint_as_float(u & 0xffff0000u);
}

__device__ __forceinline__ void unpack8(const uint4& u, float f[8]) {
    unpack_bf16(u.x, f[0], f[1]);
    unpack_bf16(u.y, f[2], f[3]);
    unpack_bf16(u.z, f[4], f[5]);
    unpack_bf16(u.w, f[6], f[7]);
}

union UH8 { unsigned int u[4]; uint4 q; f16x8 v; };

// ---- 16-output-half layer helpers (vertex; o0 wave-uniform SGPR) ----
__device__ __forceinline__ void fma_grp16(const float* __restrict__ Wt, int jj, int o0,
                                          const uint4& r, float acc[16]) {
    float x[8]; unpack8(r, x);
    const float* Wp = Wt + jj * 256 + o0;
    #pragma unroll
    for (int jo = 0; jo < 8; ++jo) {
        #pragma unroll
        for (int o = 0; o < 16; ++o) acc[o] += x[jo] * Wp[jo * 32 + o];
    }
}

__device__ __forceinline__ void layerN16(const unsigned short* col, int G, int o0,
                                         const float* __restrict__ Wt, float acc[16]) {
    uint4 cur = *(const uint4*)col;
    #pragma unroll 1
    for (int jj = 0; jj < G; ++jj) {
        uint4 nxt = (jj + 1 < G) ? *(const uint4*)(col + (jj + 1) * 8) : cur;
        fma_grp16(Wt, jj, o0, cur, acc);
        cur = nxt;
    }
}

__device__ __forceinline__ void layer2N16(const unsigned short* col, int G, int o0,
                                          const float* __restrict__ Ws,
                                          const float* __restrict__ Wd,
                                          float a1[16], float a2[16]) {
    uint4 cur = *(const uint4*)col;
    #pragma unroll 1
    for (int jj = 0; jj < G; ++jj) {
        uint4 nxt = (jj + 1 < G) ? *(const uint4*)(col + (jj + 1) * 8) : cur;
        float x[8]; unpack8(cur, x);
        const float* Wps = Ws + jj * 256 + o0;
        const float* Wpd = Wd + jj * 256 + o0;
        #pragma unroll
        for (int jo = 0; jo < 8; ++jo) {
            #pragma unroll
            for (int o = 0; o < 16; ++o) a1[o] += x[jo] * Wps[jo * 32 + o];
            #pragma unroll
            for (int o = 0; o < 16; ++o) a2[o] += x[jo] * Wpd[jo * 32 + o];
        }
        cur = nxt;
    }
}

// ---------------- K1: prep weights + zero cnt/cursor/ticket ----------------
__global__ __launch_bounds__(256) void prep_zero_kernel(
    const float* __restrict__ W1c, const float* __restrict__ W2c,
    const float* __restrict__ W1v, const float* __restrict__ W2v,
    const float* __restrict__ W1e, const float* __restrict__ W2e,
    const float* __restrict__ W1o,
    float* __restrict__ W1cT, float* __restrict__ W2cT,
    float* __restrict__ W1vT, float* __restrict__ W2vT,
    float* __restrict__ W1sT, float* __restrict__ W1dT,
    unsigned short* __restrict__ W2eh, unsigned short* __restrict__ W1oTh,
    int* __restrict__ cnt, int* __restrict__ cursor, int* __restrict__ ticket)
{
    int blk = blockIdx.x;
    if (blk < 8) {
        int i = blk * 256 + threadIdx.x;
        cnt[i] = 0;
        cursor[i] = 0;
        if (blk == 0 && threadIdx.x == 0) ticket[0] = 0;
        return;
    }
    int t = (blk - 8) * 256 + threadIdx.x;         // 0..1023
    for (int i = t; i < 32 * 24; i += 1024) W1cT[(i % 24) * 32 + i / 24] = W1c[i];
    for (int i = t; i < 32 * 32; i += 1024) W2cT[(i % 32) * 32 + i / 32] = W2c[i];
    for (int i = t; i < 32 * 64; i += 1024) W1vT[(i % 64) * 32 + i / 64] = W1v[i];
    for (int i = t; i < 32 * 32; i += 1024) W2vT[(i % 32) * 32 + i / 32] = W2v[i];
    for (int i = t; i < 32 * 68; i += 1024) {
        int o = i / 68, j = i % 68;
        if (j < 34) W1sT[j * 32 + o] = W1e[i];
        else        W1dT[(j - 34) * 32 + o] = W1e[i];
    }
    for (int i = t; i < 32 * 32; i += 1024)
        W2eh[i] = __half_as_ushort(__float2half(W2e[i]));
    for (int i = t; i < 512; i += 1024) {
        int o = i >> 4, m = i & 15;
        W1oTh[o * 32 + 2 * m]     = __half_as_ushort(__float2half(W1o[o * 32 + m]));
        W1oTh[o * 32 + 2 * m + 1] = __half_as_ushort(__float2half(W1o[o * 32 + 16 + m]));
    }
}

// ---------------- K2: count + last-block scan ----------------
__global__ __launch_bounds__(1024) void count_scan_kernel(
    const int* __restrict__ edges, int* __restrict__ cnt,
    int* __restrict__ ticket, int* __restrict__ offs)
{
    __shared__ int s[1024];
    __shared__ int lastf;
    int t = threadIdx.x;
    int e = blockIdx.x * 1024 + t;
    atomicAdd(&cnt[edges[E + e]], 1);
    __syncthreads();
    __threadfence();
    if (t == 0) lastf = (atomicAdd(ticket, 1) == 63);
    __syncthreads();
    if (!lastf) return;

    int c0 = atomicAdd(&cnt[2 * t], 0);
    int c1 = atomicAdd(&cnt[2 * t + 1], 0);
    int own = c0 + c1;
    s[t] = own;
    __syncthreads();
    int v = own;
    for (int d = 1; d < 1024; d <<= 1) {
        int add = (t >= d) ? s[t - d] : 0;
        __syncthreads();
        v += add;
        s[t] = v;
        __syncthreads();
    }
    int excl = v - own;
    offs[2 * t] = excl;
    offs[2 * t + 1] = excl + c0;
    if (t == 1023) offs[2048] = v;
}

// ---------------- K3: fill (blocks 0..255) || vertex MLP (blocks 256..767) ----------------
__global__ __launch_bounds__(256) void fill_vertex_kernel(
    const int* __restrict__ edges, const int* __restrict__ offs,
    int* __restrict__ cursor, int* __restrict__ elist,
    const float* __restrict__ vert,
    const float* __restrict__ Wx,  const float* __restrict__ bx,
    const float* __restrict__ Wy,  const float* __restrict__ by,
    const float* __restrict__ Wth, const float* __restrict__ bth,
    const float* __restrict__ b1c, const float* __restrict__ b2c,
    const float* __restrict__ b1v, const float* __restrict__ b2v,
    const float* __restrict__ b1e,
    const float* __restrict__ W1cT, const float* __restrict__ W2cT,
    const float* __restrict__ W1vT, const float* __restrict__ W2vT,
    const float* __restrict__ W1sT, const float* __restrict__ W1dT,
    unsigned int* __restrict__ asrc, unsigned int* __restrict__ adst)
{
    __shared__ unsigned short bufS[128 * 40];   // 10 KB, stride 80 B
    __shared__ unsigned short bufT[128 * 40];   // 10 KB
    __shared__ unsigned short bufC[128 * 72];   // 18.4 KB, stride 144 B

    if (blockIdx.x < 256) {                     // ---- fill branch
        int e = blockIdx.x * 256 + threadIdx.x;
        int d = edges[E + e];
        int p = atomicAdd(&cursor[d], 1);
        elist[offs[d] + p] = edges[e];
        return;
    }

    // ---- vertex branch
    int tid = threadIdx.x;
    int w = tid >> 6, lane = tid & 63;
    int g = w >> 1;
    int h = w & 1;
    int o0 = __builtin_amdgcn_readfirstlane(h << 4);
    int nl = g * 64 + lane;
    int idx = (blockIdx.x - 256) * 128 + nl;
    unsigned short* Sc = bufS + nl * 40;
    unsigned short* Tc = bufT + nl * 40;
    unsigned short* Cc = bufC + nl * 72;

    const float* v = vert + (size_t)idx * 11;
    float qk0 = v[0], qk1 = v[1], qk2 = v[2];
    float q00 = v[3], q01 = v[4], q02 = v[5];
    float qg0 = v[6], qg1 = v[7], qg2 = v[8];
    float col0 = v[9], col1 = v[10];

    for (int cfh = 0; cfh < 2; ++cfh) {
        float a0 = cfh ? qg0 : q00;
        float a1 = cfh ? qg1 : q01;
        float a2 = cfh ? qg2 : q02;
        if (h == 0) {
            #pragma unroll
            for (int i = 0; i < 4; ++i) {
                ((unsigned int*)Sc)[i] = cvtpk(
                    lrelu(qk0 * Wx[4 * i]     + a0 * Wx[4 * i + 1] + bx[2 * i]),
                    lrelu(qk0 * Wx[4 * i + 2] + a0 * Wx[4 * i + 3] + bx[2 * i + 1]));
                ((unsigned int*)Sc)[4 + i] = cvtpk(
                    lrelu(qk1 * Wy[4 * i]     + a1 * Wy[4 * i + 1] + by[2 * i]),
                    lrelu(qk1 * Wy[4 * i + 2] + a1 * Wy[4 * i + 3] + by[2 * i + 1]));
            }
        } else {
            #pragma unroll
            for (int i = 0; i < 4; ++i) {
                ((unsigned int*)Sc)[8 + i] = cvtpk(
                    lrelu(qk2 * Wth[4 * i]     + a2 * Wth[4 * i + 1] + bth[2 * i]),
                    lrelu(qk2 * Wth[4 * i + 2] + a2 * Wth[4 * i + 3] + bth[2 * i + 1]));
            }
        }
        __syncthreads();

        float hh[16];
        #pragma unroll
        for (int o = 0; o < 16; ++o) hh[o] = b1c[o0 + o];
        layerN16(Sc, 3, o0, W1cT, hh);
        #pragma unroll
        for (int q = 0; q < 8; ++q)
            ((unsigned int*)Tc)[h * 8 + q] = cvtpk(lrelu(hh[2 * q]), lrelu(hh[2 * q + 1]));
        __syncthreads();

        float gg[16];
        #pragma unroll
        for (int o = 0; o < 16; ++o) gg[o] = b2c[o0 + o];
        layerN16(Tc, 4, o0, W2cT, gg);
        #pragma unroll
        for (int q = 0; q < 8; ++q)
            ((unsigned int*)Cc)[cfh * 16 + h * 8 + q] =
                cvtpk(lrelu(gg[2 * q]), lrelu(gg[2 * q + 1]));
        __syncthreads();
    }

    float v1[16];
    #pragma unroll
    for (int o = 0; o < 16; ++o) v1[o] = b1v[o0 + o];
    layerN16(Cc, 8, o0, W1vT, v1);
    #pragma unroll
    for (int q = 0; q < 8; ++q)
        ((unsigned int*)Sc)[h * 8 + q] = cvtpk(lrelu(v1[2 * q]), lrelu(v1[2 * q + 1]));
    __syncthreads();

    float v2[16];
    #pragma unroll
    for (int o = 0; o < 16; ++o) v2[o] = b2v[o0 + o];
    layerN16(Sc, 4, o0, W2vT, v2);
    #pragma unroll
    for (int q = 0; q < 8; ++q)
        ((unsigned int*)Tc)[h * 8 + q] = cvtpk(lrelu(v2[2 * q]), lrelu(v2[2 * q + 1]));
    __syncthreads();

    float as[16], ad[16];
    #pragma unroll
    for (int o = 0; o < 16; ++o) { as[o] = 0.f; ad[o] = b1e[o0 + o]; }
    layer2N16(Tc, 4, o0, W1sT, W1dT, as, ad);
    #pragma unroll
    for (int o = 0; o < 16; ++o) {
        as[o] += col0 * W1sT[32 * 32 + o0 + o] + col1 * W1sT[33 * 32 + o0 + o];
        ad[o] += col0 * W1dT[32 * 32 + o0 + o] + col1 * W1dT[33 * 32 + o0 + o];
    }

    unsigned int* ps = asrc + ((size_t)idx << 4) + h * 8;
    unsigned int* pd = adst + ((size_t)idx << 4) + h * 8;
    #pragma unroll
    for (int q = 0; q < 8; ++q) {
        ps[q] = pkrtz(as[2 * q], as[2 * q + 1]);
        pd[q] = pkrtz(ad[2 * q], ad[2 * q + 1]);
    }
}

// ---- one 16-edge chunk step (f16 packed datapath) ----
__device__ __forceinline__ void chunk_step(
    const uint4* __restrict__ abq, const int* __restrict__ elist,
    int e0, int end, int e1, int col, int grp,
    uint4& su_c, int& src_n, const uint4& adr,
    const UH8& Bf0, const UH8& Bf1, float bias0, float bias1,
    float& s0, float& s1)
{
    uint4 su_n = abq[(src_n << 2) | grp];
    int src_n2 = elist[imin(e0 + 32 + col, e1)];

    UH8 A;
    A.u[0] = pk_addrelu(su_c.x, adr.x);
    A.u[1] = pk_addrelu(su_c.y, adr.y);
    A.u[2] = pk_addrelu(su_c.z, adr.z);
    A.u[3] = pk_addrelu(su_c.w, adr.w);
    if ((e0 + col) >= end) {
        A.u[0] = 0; A.u[1] = 0; A.u[2] = 0; A.u[3] = 0;
    }

    f32x4 acc0 = {bias0, bias0, bias0, bias0};
    f32x4 acc1 = {bias1, bias1, bias1, bias1};
    acc0 = __builtin_amdgcn_mfma_f32_16x16x32_f16(A.v, Bf0.v, acc0, 0, 0, 0);
    acc1 = __builtin_amdgcn_mfma_f32_16x16x32_f16(A.v, Bf1.v, acc1, 0, 0, 0);

    #pragma unroll
    for (int r = 0; r < 4; ++r) {
        s0 += lrelu(acc0[r]);
        s1 += lrelu(acc1[r]);
    }
    su_c = su_n;
    src_n = src_n2;
}

// ---------------- K4: edge phase (exact r15 structure) ----------------
__global__ __launch_bounds__(512) void edge_kernel(
    const unsigned int* __restrict__ asrc, const unsigned int* __restrict__ adst,
    const int* __restrict__ elist, const int* __restrict__ offs,
    const unsigned short* __restrict__ W2eh, const float* __restrict__ b2e,
    const unsigned short* __restrict__ W1oTh, const float* __restrict__ b1o,
    const float* __restrict__ W2o,  const float* __restrict__ b2o,
    float* __restrict__ fv)
{
    __shared__ unsigned int aggbuf[8 * 16 * 20];    // 10 KB
    int logical = (blockIdx.x & 7) * 64 + (blockIdx.x >> 3);   // XCD swizzle
    int b = logical >> 4;                           // batch
    int seg = logical & 15;                         // dst segment (128 dsts)
    int tid = threadIdx.x;
    int wv = tid >> 6;                              // 0..7
    int lane = tid & 63;
    int col = lane & 15;
    int grp = lane >> 4;

    const uint4* abq = (const uint4*)(asrc + (((size_t)b * NN) << 4));
    unsigned int* wvagg = aggbuf + wv * (16 * 20);

    UH8 Bf0, Bf1;
    Bf0.q = *(const uint4*)(W2eh + col * 32 + grp * 8);
    Bf1.q = *(const uint4*)(W2eh + (col + 16) * 32 + grp * 8);
    UH8 Bo0, Bo1;
    Bo0.q = *(const uint4*)(W1oTh + col * 32 + grp * 8);
    Bo1.q = *(const uint4*)(W1oTh + (col + 16) * 32 + grp * 8);
    float bias0 = b2e[col];
    float bias1 = b2e[col + 16];
    float lb0 = lrelu(bias0);
    float lb1 = lrelu(bias1);
    float b1o_lo = b1o[col];
    float b1o_hi = b1o[col + 16];
    float w2o_lo = W2o[col];
    float w2o_hi = W2o[col + 16];
    float b2oc = b2o[0];
    const unsigned int* adb = adst + (((size_t)b * NN) << 4) + grp * 4;

    int dbase = seg * 128 + wv * 16;                // 16 dsts = 8 pairs per wave
    for (int dp = 0; dp < 8; ++dp) {
        int dA = dbase + 2 * dp;
        int dB = dA + 1;
        int startA = offs[dA];
        int endA = offs[dB];
        int endB = offs[dB + 1];
        int startB = endA;
        int degA = endA - startA;
        int degB = endB - startB;
        int e1A = imax(endA - 1, 0);
        int e1B = imax(endB - 1, 0);

        const uint4 adrA = *(const uint4*)(adb + ((size_t)dA << 4));
        const uint4 adrB = *(const uint4*)(adb + ((size_t)dB << 4));

        int n = imax((degA + 15) >> 4, (degB + 15) >> 4);

        float s0A = 0.f, s1A = 0.f, s0B = 0.f, s1B = 0.f;
        if (n > 0) {
            int srcA = elist[imin(startA + col, e1A)];
            int srcB = elist[imin(startB + col, e1B)];
            uint4 suA = abq[(srcA << 2) | grp];
            uint4 suB = abq[(srcB << 2) | grp];
            int srcnA = elist[imin(startA + 16 + col, e1A)];
            int srcnB = elist[imin(startB + 16 + col, e1B)];

            for (int it = 0; it < n; ++it) {
                int e0A = startA + (it << 4);
                int e0B = startB + (it << 4);
                chunk_step(abq, elist, e0A, endA, e1A, col, grp,
                           suA, srcnA, adrA, Bf0, Bf1, bias0, bias1, s0A, s1A);
                chunk_step(abq, elist, e0B, endB, e1B, col, grp,
                           suB, srcnB, adrB, Bf0, Bf1, bias0, bias1, s0B, s1B);
            }
        }

        s0A += __shfl_xor(s0A, 16); s0A += __shfl_xor(s0A, 32);
        s1A += __shfl_xor(s1A, 16); s1A += __shfl_xor(s1A, 32);
        s0B += __shfl_xor(s0B, 16); s0B += __shfl_xor(s0B, 32);
        s1B += __shfl_xor(s1B, 16); s1B += __shfl_xor(s1B, 32);

        float padA = (float)(16 * n - degA);
        float padB = (float)(16 * n - degB);
        s0A -= padA * lb0; s1A -= padA * lb1;
        s0B -= padB * lb0; s1B -= padB * lb1;

        float invA = 1.f / fmaxf((float)degA, 1.f);
        float invB = 1.f / fmaxf((float)degB, 1.f);
        if (grp == 0) {
            wvagg[(2 * dp) * 20 + col]     = pkrtz(s0A * invA, s1A * invA);
            wvagg[(2 * dp + 1) * 20 + col] = pkrtz(s0B * invB, s1B * invB);
        }
    }

    // batched node MLP for the wave's 16 dsts (one A-frag read + 2 MFMAs)
    UH8 Ao;
    Ao.q = *(const uint4*)(wvagg + col * 20 + grp * 4);
    f32x4 acc0 = {b1o_lo, b1o_lo, b1o_lo, b1o_lo};
    f32x4 acc1 = {b1o_hi, b1o_hi, b1o_hi, b1o_hi};
    acc0 = __builtin_amdgcn_mfma_f32_16x16x32_f16(Ao.v, Bo0.v, acc0, 0, 0, 0);
    acc1 = __builtin_amdgcn_mfma_f32_16x16x32_f16(Ao.v, Bo1.v, acc1, 0, 0, 0);

    float* fvb = fv + (size_t)b * NN + dbase + grp * 4;
    #pragma unroll
    for (int r = 0; r < 4; ++r) {                          // dst = dbase + grp*4 + r
        float t = fmaxf(acc0[r], 0.f) * w2o_lo + fmaxf(acc1[r], 0.f) * w2o_hi;
        t += __shfl_xor(t, 1);
        t += __shfl_xor(t, 2);
        t += __shfl_xor(t, 4);
        t += __shfl_xor(t, 8);
        if (col == 0) fvb[r] = lrelu(t + b2oc);
    }
}

// ---------------- K5: final ----------------
__global__ __launch_bounds__(256) void final_kernel(
    const float* __restrict__ fv, const float* __restrict__ Wg,
    const float* __restrict__ bg, float* __restrict__ out)
{
    int b = blockIdx.x;
    int t = threadIdx.x;
    float p = 0.f;
    for (int n = t; n < NN; n += 256) p += fv[(size_t)b * NN + n] * Wg[n];
    __shared__ float red[256];
    red[t] = p;
    __syncthreads();
    for (int s = 128; s > 0; s >>= 1) {
        if (t < s) red[t] += red[t + s];
        __syncthreads();
    }
    if (t == 0) {
        float x = red[0] + bg[0];
        out[b] = 1.f / (1.f + expf(-x));
    }
}

extern "C" void kernel_launch(void* const* d_in, const int* in_sizes, int n_in,
                              void* d_out, int out_size, void* d_ws, size_t ws_size,
                              hipStream_t stream)
{
    const float* vert = (const float*)d_in[0];
    const int*   edges = (const int*)d_in[1];
    const float* Wx  = (const float*)d_in[2];
    const float* bx  = (const float*)d_in[3];
    const float* Wy  = (const float*)d_in[4];
    const float* by  = (const float*)d_in[5];
    const float* Wth = (const float*)d_in[6];
    const float* bth = (const float*)d_in[7];
    const float* W1c = (const float*)d_in[8];
    const float* b1c = (const float*)d_in[9];
    const float* W2c = (const float*)d_in[10];
    const float* b2c = (const float*)d_in[11];
    const float* W1v = (const float*)d_in[12];
    const float* b1v = (const float*)d_in[13];
    const float* W2v = (const float*)d_in[14];
    const float* b2v = (const float*)d_in[15];
    const float* W1e = (const float*)d_in[16];
    const float* b1e = (const float*)d_in[17];
    const float* W2e = (const float*)d_in[18];
    const float* b2e = (const float*)d_in[19];
    const float* W1o = (const float*)d_in[20];
    const float* b1o = (const float*)d_in[21];
    const float* W2o = (const float*)d_in[22];
    const float* b2o = (const float*)d_in[23];
    const float* Wg  = (const float*)d_in[24];
    const float* bg  = (const float*)d_in[25];
    float* out = (float*)d_out;

    // workspace layout (~9 MB, 16B-aligned chunks)
    char* w = (char*)d_ws;
    unsigned int* asrc = (unsigned int*)w; w += (size_t)B * NN * 32 * 2;  // f16 pairs
    unsigned int* adst = (unsigned int*)w; w += (size_t)B * NN * 32 * 2;
    float* fv   = (float*)w; w += (size_t)B * NN * 4;
    float* W1cT = (float*)w; w += 32 * 24 * 4;
    float* W2cT = (float*)w; w += 32 * 32 * 4;
    float* W1vT = (float*)w; w += 32 * 64 * 4;
    float* W2vT = (float*)w; w += 32 * 32 * 4;
    float* W1sT = (float*)w; w += 34 * 32 * 4;
    float* W1dT = (float*)w; w += 34 * 32 * 4;
    unsigned short* W2eh  = (unsigned short*)w; w += 32 * 32 * 2;
    unsigned short* W1oTh = (unsigned short*)w; w += 32 * 32 * 2;
    int* cnt    = (int*)w;   w += NN * 4;
    int* cursor = (int*)w;   w += NN * 4;
    int* offs   = (int*)w;   w += 2052 * 4;
    int* elist  = (int*)w;   w += E * 4;
    int* ticket = (int*)w;   w += 4 * 4;

    prep_zero_kernel<<<12, 256, 0, stream>>>(W1c, W2c, W1v, W2v, W1e, W2e, W1o,
                                             W1cT, W2cT, W1vT, W2vT, W1sT, W1dT,
                                             W2eh, W1oTh, cnt, cursor, ticket);

    count_scan_kernel<<<64, 1024, 0, stream>>>(edges, cnt, ticket, offs);

    fill_vertex_kernel<<<768, 256, 0, stream>>>(
        edges, offs, cursor, elist, vert,
        Wx, bx, Wy, by, Wth, bth, b1c, b2c, b1v, b2v, b1e,
        W1cT, W2cT, W1vT, W2vT, W1sT, W1dT, asrc, adst);

    edge_kernel<<<B * 16, 512, 0, stream>>>(
        asrc, adst, elist, offs, W2eh, b2e, W1oTh, b1o, W2o, b2o, fv);

    final_kernel<<<B, 256, 0, stream>>>(fv, Wg, bg, out);
}

// Round 19
// 95.556 us; speedup vs baseline: 1.3027x; 1.0995x over previous
//
#include <hip/hip_runtime.h>
#include <hip/hip_fp16.h>
#include <math.h>

constexpr int B = 32;
constexpr int NN = 2048;   // nodes
constexpr int E = 65536;   // edges
constexpr float SLOPE = 0.01f;

typedef __attribute__((ext_vector_type(8))) _Float16 f16x8;
typedef __attribute__((ext_vector_type(4))) float f32x4;

__device__ __forceinline__ float lrelu(float x) { return fmaxf(x, SLOPE * x); }
__device__ __forceinline__ int imin(int a, int b) { return a < b ? a : b; }
__device__ __forceinline__ int imax(int a, int b) { return a > b ? a : b; }

// bf16 pack (vertex-internal LDS scratch only)
__device__ __forceinline__ unsigned int cvtpk(float lo, float hi) {
    unsigned int r;
    asm("v_cvt_pk_bf16_f32 %0, %1, %2" : "=v"(r) : "v"(lo), "v"(hi));
    return r;
}
// f16 pair pack (RTZ), single instruction
__device__ __forceinline__ unsigned int pkrtz(float lo, float hi) {
    unsigned int r;
    asm("v_cvt_pkrtz_f16_f32 %0, %1, %2" : "=v"(r) : "v"(lo), "v"(hi));
    return r;
}
// packed f16: max(a+b, 0) in 2 instructions
__device__ __forceinline__ unsigned int pk_addrelu(unsigned int a, unsigned int b) {
    unsigned int s, r;
    asm("v_pk_add_f16 %0, %1, %2" : "=v"(s) : "v"(a), "v"(b));
    asm("v_pk_max_f16 %0, %1, %2" : "=v"(r) : "v"(s), "v"(0u));
    return r;
}

__device__ __forceinline__ void unpack_bf16(unsigned int u, float& lo, float& hi) {
    lo = __uint_as_float(u << 16);
    hi = __uint_as_float(u & 0xffff0000u);
}

__device__ __forceinline__ void unpack8(const uint4& u, float f[8]) {
    unpack_bf16(u.x, f[0], f[1]);
    unpack_bf16(u.y, f[2], f[3]);
    unpack_bf16(u.z, f[4], f[5]);
    unpack_bf16(u.w, f[6], f[7]);
}

union UH8 { unsigned int u[4]; uint4 q; f16x8 v; };

// ---- 16-output-half layer helpers (vertex kernel; o0 wave-uniform SGPR) ----
__device__ __forceinline__ void fma_grp16(const float* __restrict__ Wt, int jj, int o0,
                                          const uint4& r, float acc[16]) {
    float x[8]; unpack8(r, x);
    const float* Wp = Wt + jj * 256 + o0;
    #pragma unroll
    for (int jo = 0; jo < 8; ++jo) {
        #pragma unroll
        for (int o = 0; o < 16; ++o) acc[o] += x[jo] * Wp[jo * 32 + o];
    }
}

__device__ __forceinline__ void layerN16(const unsigned short* col, int G, int o0,
                                         const float* __restrict__ Wt, float acc[16]) {
    uint4 cur = *(const uint4*)col;
    #pragma unroll 1
    for (int jj = 0; jj < G; ++jj) {
        uint4 nxt = (jj + 1 < G) ? *(const uint4*)(col + (jj + 1) * 8) : cur;
        fma_grp16(Wt, jj, o0, cur, acc);
        cur = nxt;
    }
}

__device__ __forceinline__ void layer2N16(const unsigned short* col, int G, int o0,
                                          const float* __restrict__ Ws,
                                          const float* __restrict__ Wd,
                                          float a1[16], float a2[16]) {
    uint4 cur = *(const uint4*)col;
    #pragma unroll 1
    for (int jj = 0; jj < G; ++jj) {
        uint4 nxt = (jj + 1 < G) ? *(const uint4*)(col + (jj + 1) * 8) : cur;
        float x[8]; unpack8(cur, x);
        const float* Wps = Ws + jj * 256 + o0;
        const float* Wpd = Wd + jj * 256 + o0;
        #pragma unroll
        for (int jo = 0; jo < 8; ++jo) {
            #pragma unroll
            for (int o = 0; o < 16; ++o) a1[o] += x[jo] * Wps[jo * 32 + o];
            #pragma unroll
            for (int o = 0; o < 16; ++o) a2[o] += x[jo] * Wpd[jo * 32 + o];
        }
        cur = nxt;
    }
}

// ---------------- prep (blocks 8..11) + CSR-counter zero (blocks 0..7) ----------------
__global__ __launch_bounds__(256) void prep_zero_kernel(
    const float* __restrict__ W1c, const float* __restrict__ W2c,
    const float* __restrict__ W1v, const float* __restrict__ W2v,
    const float* __restrict__ W1e, const float* __restrict__ W2e,
    const float* __restrict__ W1o,
    float* __restrict__ W1cT, float* __restrict__ W2cT,
    float* __restrict__ W1vT, float* __restrict__ W2vT,
    float* __restrict__ W1sT, float* __restrict__ W1dT,
    unsigned short* __restrict__ W2eh, unsigned short* __restrict__ W1oTh,
    int* __restrict__ cnt, int* __restrict__ cursor)
{
    int blk = blockIdx.x;
    if (blk < 8) {
        int i = blk * 256 + threadIdx.x;
        cnt[i] = 0;
        cursor[i] = 0;
        return;
    }
    int t = (blk - 8) * 256 + threadIdx.x;         // 0..1023
    for (int i = t; i < 32 * 24; i += 1024) W1cT[(i % 24) * 32 + i / 24] = W1c[i];
    for (int i = t; i < 32 * 32; i += 1024) W2cT[(i % 32) * 32 + i / 32] = W2c[i];
    for (int i = t; i < 32 * 64; i += 1024) W1vT[(i % 64) * 32 + i / 64] = W1v[i];
    for (int i = t; i < 32 * 32; i += 1024) W2vT[(i % 32) * 32 + i / 32] = W2v[i];
    for (int i = t; i < 32 * 68; i += 1024) {
        int o = i / 68, j = i % 68;
        if (j < 34) W1sT[j * 32 + o] = W1e[i];
        else        W1dT[(j - 34) * 32 + o] = W1e[i];
    }
    for (int i = t; i < 32 * 32; i += 1024) {       // W2e row-major f32 -> f16
        __half hv = __float2half(W2e[i]);
        W2eh[i] = __half_as_ushort(hv);
    }
    // W1oTh[o][k'] f16, k' = 2m -> W1o[o][m], 2m+1 -> W1o[o][16+m]
    for (int i = t; i < 512; i += 1024) {
        int o = i >> 4, m = i & 15;
        W1oTh[o * 32 + 2 * m]     = __half_as_ushort(__float2half(W1o[o * 32 + m]));
        W1oTh[o * 32 + 2 * m + 1] = __half_as_ushort(__float2half(W1o[o * 32 + 16 + m]));
    }
}

// ---------------- CSR build ----------------
__global__ __launch_bounds__(256) void count_kernel(const int* __restrict__ edges, int* __restrict__ cnt)
{
    int e = blockIdx.x * 256 + threadIdx.x;
    if (e < E) atomicAdd(&cnt[edges[E + e]], 1);
}

__global__ __launch_bounds__(1024) void scan_kernel(const int* __restrict__ cnt, int* __restrict__ offs)
{
    __shared__ int s[1024];
    int t = threadIdx.x;
    int c0 = cnt[2 * t], c1 = cnt[2 * t + 1];
    int own = c0 + c1;
    s[t] = own;
    __syncthreads();
    int v = own;
    for (int d = 1; d < 1024; d <<= 1) {
        int add = (t >= d) ? s[t - d] : 0;
        __syncthreads();
        v += add;
        s[t] = v;
        __syncthreads();
    }
    int excl = v - own;
    offs[2 * t] = excl;
    offs[2 * t + 1] = excl + c0;
    if (t == 1023) offs[2048] = v;
}

__global__ __launch_bounds__(256) void fill_kernel(
    const int* __restrict__ edges, const int* __restrict__ offs,
    int* __restrict__ cursor, int* __restrict__ elist)
{
    int e = blockIdx.x * 256 + threadIdx.x;
    if (e < E) {
        int d = edges[E + e];
        int p = atomicAdd(&cursor[d], 1);
        elist[offs[d] + p] = edges[e];
    }
}

// ---------------- vertex MLP: 2 threads/node, split by WAVE (r11 structure;
//                  output pack switched to f16) ----------------
__global__ __launch_bounds__(256) void vertex_kernel(
    const float* __restrict__ vert,
    const float* __restrict__ Wx,  const float* __restrict__ bx,
    const float* __restrict__ Wy,  const float* __restrict__ by,
    const float* __restrict__ Wth, const float* __restrict__ bth,
    const float* __restrict__ b1c, const float* __restrict__ b2c,
    const float* __restrict__ b1v, const float* __restrict__ b2v,
    const float* __restrict__ b1e,
    const float* __restrict__ W1cT, const float* __restrict__ W2cT,
    const float* __restrict__ W1vT, const float* __restrict__ W2vT,
    const float* __restrict__ W1sT, const float* __restrict__ W1dT,
    unsigned int* __restrict__ asrc, unsigned int* __restrict__ adst)
{
    __shared__ unsigned short bufS[128 * 40];   // 10 KB, stride 80 B
    __shared__ unsigned short bufT[128 * 40];   // 10 KB
    __shared__ unsigned short bufC[128 * 72];   // 18.4 KB, stride 144 B
    int tid = threadIdx.x;
    int w = tid >> 6, lane = tid & 63;
    int g = w >> 1;
    int h = w & 1;
    int o0 = __builtin_amdgcn_readfirstlane(h << 4);
    int nl = g * 64 + lane;
    int idx = blockIdx.x * 128 + nl;
    unsigned short* Sc = bufS + nl * 40;
    unsigned short* Tc = bufT + nl * 40;
    unsigned short* Cc = bufC + nl * 72;

    const float* v = vert + (size_t)idx * 11;
    float qk0 = v[0], qk1 = v[1], qk2 = v[2];
    float q00 = v[3], q01 = v[4], q02 = v[5];
    float qg0 = v[6], qg1 = v[7], qg2 = v[8];
    float col0 = v[9], col1 = v[10];

    for (int cfh = 0; cfh < 2; ++cfh) {
        float a0 = cfh ? qg0 : q00;
        float a1 = cfh ? qg1 : q01;
        float a2 = cfh ? qg2 : q02;
        if (h == 0) {
            #pragma unroll
            for (int i = 0; i < 4; ++i) {
                ((unsigned int*)Sc)[i] = cvtpk(
                    lrelu(qk0 * Wx[4 * i]     + a0 * Wx[4 * i + 1] + bx[2 * i]),
                    lrelu(qk0 * Wx[4 * i + 2] + a0 * Wx[4 * i + 3] + bx[2 * i + 1]));
                ((unsigned int*)Sc)[4 + i] = cvtpk(
                    lrelu(qk1 * Wy[4 * i]     + a1 * Wy[4 * i + 1] + by[2 * i]),
                    lrelu(qk1 * Wy[4 * i + 2] + a1 * Wy[4 * i + 3] + by[2 * i + 1]));
            }
        } else {
            #pragma unroll
            for (int i = 0; i < 4; ++i) {
                ((unsigned int*)Sc)[8 + i] = cvtpk(
                    lrelu(qk2 * Wth[4 * i]     + a2 * Wth[4 * i + 1] + bth[2 * i]),
                    lrelu(qk2 * Wth[4 * i + 2] + a2 * Wth[4 * i + 3] + bth[2 * i + 1]));
            }
        }
        __syncthreads();

        float hh[16];
        #pragma unroll
        for (int o = 0; o < 16; ++o) hh[o] = b1c[o0 + o];
        layerN16(Sc, 3, o0, W1cT, hh);
        #pragma unroll
        for (int q = 0; q < 8; ++q)
            ((unsigned int*)Tc)[h * 8 + q] = cvtpk(lrelu(hh[2 * q]), lrelu(hh[2 * q + 1]));
        __syncthreads();

        float gg[16];
        #pragma unroll
        for (int o = 0; o < 16; ++o) gg[o] = b2c[o0 + o];
        layerN16(Tc, 4, o0, W2cT, gg);
        #pragma unroll
        for (int q = 0; q < 8; ++q)
            ((unsigned int*)Cc)[cfh * 16 + h * 8 + q] =
                cvtpk(lrelu(gg[2 * q]), lrelu(gg[2 * q + 1]));
        __syncthreads();
    }

    float v1[16];
    #pragma unroll
    for (int o = 0; o < 16; ++o) v1[o] = b1v[o0 + o];
    layerN16(Cc, 8, o0, W1vT, v1);
    #pragma unroll
    for (int q = 0; q < 8; ++q)
        ((unsigned int*)Sc)[h * 8 + q] = cvtpk(lrelu(v1[2 * q]), lrelu(v1[2 * q + 1]));
    __syncthreads();

    float v2[16];
    #pragma unroll
    for (int o = 0; o < 16; ++o) v2[o] = b2v[o0 + o];
    layerN16(Sc, 4, o0, W2vT, v2);
    #pragma unroll
    for (int q = 0; q < 8; ++q)
        ((unsigned int*)Tc)[h * 8 + q] = cvtpk(lrelu(v2[2 * q]), lrelu(v2[2 * q + 1]));
    __syncthreads();

    float as[16], ad[16];
    #pragma unroll
    for (int o = 0; o < 16; ++o) { as[o] = 0.f; ad[o] = b1e[o0 + o]; }
    layer2N16(Tc, 4, o0, W1sT, W1dT, as, ad);
    #pragma unroll
    for (int o = 0; o < 16; ++o) {
        as[o] += col0 * W1sT[32 * 32 + o0 + o] + col1 * W1sT[33 * 32 + o0 + o];
        ad[o] += col0 * W1dT[32 * 32 + o0 + o] + col1 * W1dT[33 * 32 + o0 + o];
    }

    unsigned int* ps = asrc + ((size_t)idx << 4) + h * 8;
    unsigned int* pd = adst + ((size_t)idx << 4) + h * 8;
    #pragma unroll
    for (int q = 0; q < 8; ++q) {
        ps[q] = pkrtz(as[2 * q], as[2 * q + 1]);    // f16 pairs
        pd[q] = pkrtz(ad[2 * q], ad[2 * q + 1]);
    }
}

// ---- one 16-edge chunk step (f16 packed datapath) ----
__device__ __forceinline__ void chunk_step(
    const uint4* __restrict__ abq, const int* __restrict__ elist,
    int e0, int end, int e1, int col, int grp,
    uint4& su_c, int& src_n, const uint4& adr,
    const UH8& Bf0, const UH8& Bf1, float bias0, float bias1,
    float& s0, float& s1)
{
    // prefetch next chunk's gather (L2) + next-next elist
    uint4 su_n = abq[(src_n << 2) | grp];
    int src_n2 = elist[imin(e0 + 32 + col, e1)];

    UH8 A;                                           // relu(asrc+adst): 8 packed instr
    A.u[0] = pk_addrelu(su_c.x, adr.x);
    A.u[1] = pk_addrelu(su_c.y, adr.y);
    A.u[2] = pk_addrelu(su_c.z, adr.z);
    A.u[3] = pk_addrelu(su_c.w, adr.w);
    if ((e0 + col) >= end) {                         // zero invalid lane's A row
        A.u[0] = 0; A.u[1] = 0; A.u[2] = 0; A.u[3] = 0;
    }

    f32x4 acc0 = {bias0, bias0, bias0, bias0};
    f32x4 acc1 = {bias1, bias1, bias1, bias1};
    acc0 = __builtin_amdgcn_mfma_f32_16x16x32_f16(A.v, Bf0.v, acc0, 0, 0, 0);
    acc1 = __builtin_amdgcn_mfma_f32_16x16x32_f16(A.v, Bf1.v, acc1, 0, 0, 0);

    #pragma unroll
    for (int r = 0; r < 4; ++r) {
        s0 += lrelu(acc0[r]);
        s1 += lrelu(acc1[r]);
    }
    su_c = su_n;
    src_n = src_n2;
}

// ---------------- edge phase: L2 gathers, 512-thr blocks, two interleaved dst
//                  streams, MFMA-batched node-MLP epilogue (16 dsts/wave) ----------------
__global__ __launch_bounds__(512) void edge_kernel(
    const unsigned int* __restrict__ asrc, const unsigned int* __restrict__ adst,
    const int* __restrict__ elist, const int* __restrict__ offs,
    const unsigned short* __restrict__ W2eh, const float* __restrict__ b2e,
    const unsigned short* __restrict__ W1oTh, const float* __restrict__ b1o,
    const float* __restrict__ W2o,  const float* __restrict__ b2o,
    float* __restrict__ fv)
{
    __shared__ unsigned int aggbuf[8 * 16 * 20];    // 10 KB: 8 waves x 16 dsts x 80B rows
    int logical = (blockIdx.x & 7) * 64 + (blockIdx.x >> 3);   // XCD swizzle
    int b = logical >> 4;                           // batch
    int seg = logical & 15;                         // dst segment (128 dsts)
    int tid = threadIdx.x;
    int wv = tid >> 6;                              // 0..7
    int lane = tid & 63;
    int col = lane & 15;
    int grp = lane >> 4;

    const uint4* abq = (const uint4*)(asrc + (((size_t)b * NN) << 4));
    unsigned int* wvagg = aggbuf + wv * (16 * 20);

    UH8 Bf0, Bf1;
    Bf0.q = *(const uint4*)(W2eh + col * 32 + grp * 8);
    Bf1.q = *(const uint4*)(W2eh + (col + 16) * 32 + grp * 8);
    UH8 Bo0, Bo1;                                   // node-MLP B fragments
    Bo0.q = *(const uint4*)(W1oTh + col * 32 + grp * 8);
    Bo1.q = *(const uint4*)(W1oTh + (col + 16) * 32 + grp * 8);
    float bias0 = b2e[col];
    float bias1 = b2e[col + 16];
    float lb0 = lrelu(bias0);
    float lb1 = lrelu(bias1);
    float b1o_lo = b1o[col];
    float b1o_hi = b1o[col + 16];
    float w2o_lo = W2o[col];
    float w2o_hi = W2o[col + 16];
    float b2oc = b2o[0];
    const unsigned int* adb = adst + (((size_t)b * NN) << 4) + grp * 4;

    int dbase = seg * 128 + wv * 16;                // 16 dsts = 8 pairs per wave
    for (int dp = 0; dp < 8; ++dp) {
        int dA = dbase + 2 * dp;
        int dB = dA + 1;
        int startA = offs[dA];
        int endA = offs[dB];
        int endB = offs[dB + 1];
        int startB = endA;
        int degA = endA - startA;
        int degB = endB - startB;
        int e1A = imax(endA - 1, 0);
        int e1B = imax(endB - 1, 0);

        const uint4 adrA = *(const uint4*)(adb + ((size_t)dA << 4));   // f16 packed
        const uint4 adrB = *(const uint4*)(adb + ((size_t)dB << 4));

        int n = imax((degA + 15) >> 4, (degB + 15) >> 4);

        float s0A = 0.f, s1A = 0.f, s0B = 0.f, s1B = 0.f;
        if (n > 0) {
            int srcA = elist[imin(startA + col, e1A)];
            int srcB = elist[imin(startB + col, e1B)];
            uint4 suA = abq[(srcA << 2) | grp];
            uint4 suB = abq[(srcB << 2) | grp];
            int srcnA = elist[imin(startA + 16 + col, e1A)];
            int srcnB = elist[imin(startB + 16 + col, e1B)];

            for (int it = 0; it < n; ++it) {
                int e0A = startA + (it << 4);
                int e0B = startB + (it << 4);
                chunk_step(abq, elist, e0A, endA, e1A, col, grp,
                           suA, srcnA, adrA, Bf0, Bf1, bias0, bias1, s0A, s1A);
                chunk_step(abq, elist, e0B, endB, e1B, col, grp,
                           suB, srcnB, adrB, Bf0, Bf1, bias0, bias1, s0B, s1B);
            }
        }

        s0A += __shfl_xor(s0A, 16); s0A += __shfl_xor(s0A, 32);
        s1A += __shfl_xor(s1A, 16); s1A += __shfl_xor(s1A, 32);
        s0B += __shfl_xor(s0B, 16); s0B += __shfl_xor(s0B, 32);
        s1B += __shfl_xor(s1B, 16); s1B += __shfl_xor(s1B, 32);

        float padA = (float)(16 * n - degA);
        float padB = (float)(16 * n - degB);
        s0A -= padA * lb0; s1A -= padA * lb1;
        s0B -= padB * lb0; s1B -= padB * lb1;

        float invA = 1.f / fmaxf((float)degA, 1.f);
        float invB = 1.f / fmaxf((float)degB, 1.f);
        // write agg rows (f16, feature-interleaved k': 2m=feat m, 2m+1=feat 16+m)
        if (grp == 0) {
            wvagg[(2 * dp) * 20 + col]     = pkrtz(s0A * invA, s1A * invA);
            wvagg[(2 * dp + 1) * 20 + col] = pkrtz(s0B * invB, s1B * invB);
        }
    }

    // ---- batched node MLP for the wave's 16 dsts (one A-frag read + 2 MFMAs)
    UH8 Ao;
    Ao.q = *(const uint4*)(wvagg + col * 20 + grp * 4);   // row=col(dst), k'=grp*8..+7
    f32x4 acc0 = {b1o_lo, b1o_lo, b1o_lo, b1o_lo};        // f1[dst][o=col]
    f32x4 acc1 = {b1o_hi, b1o_hi, b1o_hi, b1o_hi};        // f1[dst][o=col+16]
    acc0 = __builtin_amdgcn_mfma_f32_16x16x32_f16(Ao.v, Bo0.v, acc0, 0, 0, 0);
    acc1 = __builtin_amdgcn_mfma_f32_16x16x32_f16(Ao.v, Bo1.v, acc1, 0, 0, 0);

    float* fvb = fv + (size_t)b * NN + dbase + grp * 4;
    #pragma unroll
    for (int r = 0; r < 4; ++r) {                          // dst = dbase + grp*4 + r
        float t = fmaxf(acc0[r], 0.f) * w2o_lo + fmaxf(acc1[r], 0.f) * w2o_hi;
        t += __shfl_xor(t, 1);
        t += __shfl_xor(t, 2);
        t += __shfl_xor(t, 4);
        t += __shfl_xor(t, 8);
        if (col == 0) fvb[r] = lrelu(t + b2oc);
    }
}

// ---------------- final: out[b] = sigmoid(dot(fv[b,:], Wg) + bg) ----------------
__global__ __launch_bounds__(256) void final_kernel(
    const float* __restrict__ fv, const float* __restrict__ Wg,
    const float* __restrict__ bg, float* __restrict__ out)
{
    int b = blockIdx.x;
    int t = threadIdx.x;
    float p = 0.f;
    for (int n = t; n < NN; n += 256) p += fv[(size_t)b * NN + n] * Wg[n];
    __shared__ float red[256];
    red[t] = p;
    __syncthreads();
    for (int s = 128; s > 0; s >>= 1) {
        if (t < s) red[t] += red[t + s];
        __syncthreads();
    }
    if (t == 0) {
        float x = red[0] + bg[0];
        out[b] = 1.f / (1.f + expf(-x));
    }
}

extern "C" void kernel_launch(void* const* d_in, const int* in_sizes, int n_in,
                              void* d_out, int out_size, void* d_ws, size_t ws_size,
                              hipStream_t stream)
{
    const float* vert = (const float*)d_in[0];
    const int*   edges = (const int*)d_in[1];
    const float* Wx  = (const float*)d_in[2];
    const float* bx  = (const float*)d_in[3];
    const float* Wy  = (const float*)d_in[4];
    const float* by  = (const float*)d_in[5];
    const float* Wth = (const float*)d_in[6];
    const float* bth = (const float*)d_in[7];
    const float* W1c = (const float*)d_in[8];
    const float* b1c = (const float*)d_in[9];
    const float* W2c = (const float*)d_in[10];
    const float* b2c = (const float*)d_in[11];
    const float* W1v = (const float*)d_in[12];
    const float* b1v = (const float*)d_in[13];
    const float* W2v = (const float*)d_in[14];
    const float* b2v = (const float*)d_in[15];
    const float* W1e = (const float*)d_in[16];
    const float* b1e = (const float*)d_in[17];
    const float* W2e = (const float*)d_in[18];
    const float* b2e = (const float*)d_in[19];
    const float* W1o = (const float*)d_in[20];
    const float* b1o = (const float*)d_in[21];
    const float* W2o = (const float*)d_in[22];
    const float* b2o = (const float*)d_in[23];
    const float* Wg  = (const float*)d_in[24];
    const float* bg  = (const float*)d_in[25];
    float* out = (float*)d_out;

    // workspace layout (~9 MB, all chunks 16B-aligned)
    char* w = (char*)d_ws;
    unsigned int* asrc = (unsigned int*)w; w += (size_t)B * NN * 32 * 2;  // f16 pairs
    unsigned int* adst = (unsigned int*)w; w += (size_t)B * NN * 32 * 2;
    float* fv   = (float*)w; w += (size_t)B * NN * 4;
    float* W1cT = (float*)w; w += 32 * 24 * 4;
    float* W2cT = (float*)w; w += 32 * 32 * 4;
    float* W1vT = (float*)w; w += 32 * 64 * 4;
    float* W2vT = (float*)w; w += 32 * 32 * 4;
    float* W1sT = (float*)w; w += 34 * 32 * 4;
    float* W1dT = (float*)w; w += 34 * 32 * 4;
    unsigned short* W2eh  = (unsigned short*)w; w += 32 * 32 * 2;
    unsigned short* W1oTh = (unsigned short*)w; w += 32 * 32 * 2;
    int* cnt    = (int*)w;   w += NN * 4;
    int* cursor = (int*)w;   w += NN * 4;
    int* offs   = (int*)w;   w += 2052 * 4;
    int* elist  = (int*)w;   w += E * 4;

    prep_zero_kernel<<<12, 256, 0, stream>>>(W1c, W2c, W1v, W2v, W1e, W2e, W1o,
                                             W1cT, W2cT, W1vT, W2vT, W1sT, W1dT,
                                             W2eh, W1oTh, cnt, cursor);
    count_kernel<<<E / 256, 256, 0, stream>>>(edges, cnt);
    scan_kernel<<<1, 1024, 0, stream>>>(cnt, offs);
    fill_kernel<<<E / 256, 256, 0, stream>>>(edges, offs, cursor, elist);

    vertex_kernel<<<(B * NN) / 128, 256, 0, stream>>>(
        vert, Wx, bx, Wy, by, Wth, bth, b1c, b2c, b1v, b2v, b1e,
        W1cT, W2cT, W1vT, W2vT, W1sT, W1dT, asrc, adst);

    edge_kernel<<<B * 16, 512, 0, stream>>>(
        asrc, adst, elist, offs, W2eh, b2e, W1oTh, b1o, W2o, b2o, fv);

    final_kernel<<<B, 256, 0, stream>>>(fv, Wg, bg, out);
}

// Round 21
// 92.317 us; speedup vs baseline: 1.3485x; 1.0351x over previous
//
#include <hip/hip_runtime.h>
#include <hip/hip_fp16.h>
#include <math.h>

constexpr int B = 32;
constexpr int NN = 2048;   // nodes
constexpr int E = 65536;   // edges
constexpr float SLOPE = 0.01f;

typedef __attribute__((ext_vector_type(8))) _Float16 f16x8;
typedef __attribute__((ext_vector_type(2))) _Float16 f16x2;
typedef __attribute__((ext_vector_type(4))) float f32x4;

__device__ __forceinline__ float lrelu(float x) { return fmaxf(x, SLOPE * x); }
__device__ __forceinline__ int imin(int a, int b) { return a < b ? a : b; }
__device__ __forceinline__ int imax(int a, int b) { return a > b ? a : b; }

// f16 pair pack (RTZ), single instruction
__device__ __forceinline__ unsigned int pkrtz(float lo, float hi) {
    unsigned int r;
    asm("v_cvt_pkrtz_f16_f32 %0, %1, %2" : "=v"(r) : "v"(lo), "v"(hi));
    return r;
}
// packed f16: max(a+b, 0) in 2 instructions
__device__ __forceinline__ unsigned int pk_addrelu(unsigned int a, unsigned int b) {
    unsigned int s, r;
    asm("v_pk_add_f16 %0, %1, %2" : "=v"(s) : "v"(a), "v"(b));
    asm("v_pk_max_f16 %0, %1, %2" : "=v"(r) : "v"(s), "v"(0u));
    return r;
}
// f16 pair RNE pack (prep, precision)
__device__ __forceinline__ unsigned int pkh2(float lo, float hi) {
    return (unsigned int)__half_as_ushort(__float2half(lo)) |
           ((unsigned int)__half_as_ushort(__float2half(hi)) << 16);
}

// 2xf16 dot with f32 accumulate: one VOP3P instr where available
__device__ __forceinline__ float dot2(unsigned int x, unsigned int w, float c) {
#if __has_builtin(__builtin_amdgcn_fdot2)
    union Uh { unsigned int u; f16x2 h; };
    Uh a; a.u = x;
    Uh b; b.u = w;
    return __builtin_amdgcn_fdot2(a.h, b.h, c, false);
#else
    float xl = __half2float(__ushort_as_half((unsigned short)(x & 0xffffu)));
    float xh = __half2float(__ushort_as_half((unsigned short)(x >> 16)));
    float wl = __half2float(__ushort_as_half((unsigned short)(w & 0xffffu)));
    float wh = __half2float(__ushort_as_half((unsigned short)(w >> 16)));
    return c + xl * wl + xh * wh;
#endif
}

union UH8 { unsigned int u[4]; uint4 q; f16x8 v; };

// ---- pair-packed layer helpers (vertex; o0 wave-uniform SGPR) ----
// col: per-thread LDS column of u32 f16-pairs; G groups of 4 pairs (8 feats).
// Wp[jp*32 + o] = (W[o][2jp], W[o][2jp+1]) f16 pair.
__device__ __forceinline__ void layerP16(const unsigned int* col, int G, int o0,
                                         const unsigned int* __restrict__ Wp,
                                         float acc[16]) {
    uint4 cur = *(const uint4*)col;
    #pragma unroll 1
    for (int jj = 0; jj < G; ++jj) {
        uint4 nxt = (jj + 1 < G) ? *(const uint4*)(col + (jj + 1) * 4) : cur;
        const unsigned int* Wq = Wp + jj * 128 + o0;
        #pragma unroll
        for (int o = 0; o < 16; ++o) acc[o] = dot2(cur.x, Wq[o], acc[o]);
        #pragma unroll
        for (int o = 0; o < 16; ++o) acc[o] = dot2(cur.y, Wq[32 + o], acc[o]);
        #pragma unroll
        for (int o = 0; o < 16; ++o) acc[o] = dot2(cur.z, Wq[64 + o], acc[o]);
        #pragma unroll
        for (int o = 0; o < 16; ++o) acc[o] = dot2(cur.w, Wq[96 + o], acc[o]);
        cur = nxt;
    }
}

__device__ __forceinline__ void layer2P16(const unsigned int* col, int G, int o0,
                                          const unsigned int* __restrict__ Ws,
                                          const unsigned int* __restrict__ Wd,
                                          float a1[16], float a2[16]) {
    uint4 cur = *(const uint4*)col;
    #pragma unroll 1
    for (int jj = 0; jj < G; ++jj) {
        uint4 nxt = (jj + 1 < G) ? *(const uint4*)(col + (jj + 1) * 4) : cur;
        const unsigned int* Wqs = Ws + jj * 128 + o0;
        const unsigned int* Wqd = Wd + jj * 128 + o0;
        #pragma unroll
        for (int o = 0; o < 16; ++o) a1[o] = dot2(cur.x, Wqs[o], a1[o]);
        #pragma unroll
        for (int o = 0; o < 16; ++o) a2[o] = dot2(cur.x, Wqd[o], a2[o]);
        #pragma unroll
        for (int o = 0; o < 16; ++o) a1[o] = dot2(cur.y, Wqs[32 + o], a1[o]);
        #pragma unroll
        for (int o = 0; o < 16; ++o) a2[o] = dot2(cur.y, Wqd[32 + o], a2[o]);
        #pragma unroll
        for (int o = 0; o < 16; ++o) a1[o] = dot2(cur.z, Wqs[64 + o], a1[o]);
        #pragma unroll
        for (int o = 0; o < 16; ++o) a2[o] = dot2(cur.z, Wqd[64 + o], a2[o]);
        #pragma unroll
        for (int o = 0; o < 16; ++o) a1[o] = dot2(cur.w, Wqs[96 + o], a1[o]);
        #pragma unroll
        for (int o = 0; o < 16; ++o) a2[o] = dot2(cur.w, Wqd[96 + o], a2[o]);
        cur = nxt;
    }
}

// ---------------- prep (blocks 8..11) + CSR-counter zero (blocks 0..7) ----------------
__global__ __launch_bounds__(256) void prep_zero_kernel(
    const float* __restrict__ W1c, const float* __restrict__ W2c,
    const float* __restrict__ W1v, const float* __restrict__ W2v,
    const float* __restrict__ W1e, const float* __restrict__ W2e,
    const float* __restrict__ W1o,
    unsigned int* __restrict__ W1cTp, unsigned int* __restrict__ W2cTp,
    unsigned int* __restrict__ W1vTp, unsigned int* __restrict__ W2vTp,
    unsigned int* __restrict__ W1sTp, unsigned int* __restrict__ W1dTp,
    unsigned short* __restrict__ W2eh, unsigned short* __restrict__ W1oTh,
    int* __restrict__ cnt, int* __restrict__ cursor)
{
    int blk = blockIdx.x;
    if (blk < 8) {
        int i = blk * 256 + threadIdx.x;
        cnt[i] = 0;
        cursor[i] = 0;
        return;
    }
    int t = (blk - 8) * 256 + threadIdx.x;         // 0..1023
    // pair-packed f16 weights for vertex: Wp[jp*32+o] = (W[o][2jp], W[o][2jp+1])
    for (int i = t; i < 12 * 32; i += 1024) {       // W1c: [32][24]
        int jp = i >> 5, o = i & 31;
        W1cTp[i] = pkh2(W1c[o * 24 + 2 * jp], W1c[o * 24 + 2 * jp + 1]);
    }
    for (int i = t; i < 16 * 32; i += 1024) {       // W2c: [32][32]
        int jp = i >> 5, o = i & 31;
        W2cTp[i] = pkh2(W2c[o * 32 + 2 * jp], W2c[o * 32 + 2 * jp + 1]);
    }
    for (int i = t; i < 32 * 32; i += 1024) {       // W1v: [32][64]
        int jp = i >> 5, o = i & 31;
        W1vTp[i] = pkh2(W1v[o * 64 + 2 * jp], W1v[o * 64 + 2 * jp + 1]);
    }
    for (int i = t; i < 16 * 32; i += 1024) {       // W2v: [32][32]
        int jp = i >> 5, o = i & 31;
        W2vTp[i] = pkh2(W2v[o * 32 + 2 * jp], W2v[o * 32 + 2 * jp + 1]);
    }
    for (int i = t; i < 17 * 32; i += 1024) {       // W1e src half: [32][68] j<34
        int jp = i >> 5, o = i & 31;
        W1sTp[i] = pkh2(W1e[o * 68 + 2 * jp], W1e[o * 68 + 2 * jp + 1]);
    }
    for (int i = t; i < 17 * 32; i += 1024) {       // W1e dst half: j>=34
        int jp = i >> 5, o = i & 31;
        W1dTp[i] = pkh2(W1e[o * 68 + 34 + 2 * jp], W1e[o * 68 + 34 + 2 * jp + 1]);
    }
    for (int i = t; i < 32 * 32; i += 1024) {       // W2e row-major f32 -> f16
        W2eh[i] = __half_as_ushort(__float2half(W2e[i]));
    }
    // W1oTh[o][k'] f16, k' = 2m -> W1o[o][m], 2m+1 -> W1o[o][16+m]
    for (int i = t; i < 512; i += 1024) {
        int o = i >> 4, m = i & 15;
        W1oTh[o * 32 + 2 * m]     = __half_as_ushort(__float2half(W1o[o * 32 + m]));
        W1oTh[o * 32 + 2 * m + 1] = __half_as_ushort(__float2half(W1o[o * 32 + 16 + m]));
    }
}

// ---------------- CSR build ----------------
__global__ __launch_bounds__(256) void count_kernel(const int* __restrict__ edges, int* __restrict__ cnt)
{
    int e = blockIdx.x * 256 + threadIdx.x;
    if (e < E) atomicAdd(&cnt[edges[E + e]], 1);
}

__global__ __launch_bounds__(1024) void scan_kernel(const int* __restrict__ cnt, int* __restrict__ offs)
{
    __shared__ int s[1024];
    int t = threadIdx.x;
    int c0 = cnt[2 * t], c1 = cnt[2 * t + 1];
    int own = c0 + c1;
    s[t] = own;
    __syncthreads();
    int v = own;
    for (int d = 1; d < 1024; d <<= 1) {
        int add = (t >= d) ? s[t - d] : 0;
        __syncthreads();
        v += add;
        s[t] = v;
        __syncthreads();
    }
    int excl = v - own;
    offs[2 * t] = excl;
    offs[2 * t + 1] = excl + c0;
    if (t == 1023) offs[2048] = v;
}

__global__ __launch_bounds__(256) void fill_kernel(
    const int* __restrict__ edges, const int* __restrict__ offs,
    int* __restrict__ cursor, int* __restrict__ elist)
{
    int e = blockIdx.x * 256 + threadIdx.x;
    if (e < E) {
        int d = edges[E + e];
        int p = atomicAdd(&cursor[d], 1);
        elist[offs[d] + p] = edges[e];
    }
}

// ---------------- vertex MLP: 2 threads/node, wave-split halves,
//                  f16 pair activations + v_dot2_f32_f16 layers ----------------
__global__ __launch_bounds__(256) void vertex_kernel(
    const float* __restrict__ vert,
    const float* __restrict__ Wx,  const float* __restrict__ bx,
    const float* __restrict__ Wy,  const float* __restrict__ by,
    const float* __restrict__ Wth, const float* __restrict__ bth,
    const float* __restrict__ b1c, const float* __restrict__ b2c,
    const float* __restrict__ b1v, const float* __restrict__ b2v,
    const float* __restrict__ b1e,
    const unsigned int* __restrict__ W1cTp, const unsigned int* __restrict__ W2cTp,
    const unsigned int* __restrict__ W1vTp, const unsigned int* __restrict__ W2vTp,
    const unsigned int* __restrict__ W1sTp, const unsigned int* __restrict__ W1dTp,
    unsigned int* __restrict__ asrc, unsigned int* __restrict__ adst)
{
    __shared__ unsigned int bufS[128 * 20];   // 10 KB, stride 80 B (16 pairs used)
    __shared__ unsigned int bufT[128 * 20];   // 10 KB
    __shared__ unsigned int bufC[128 * 36];   // 18 KB, stride 144 B (32 pairs used)
    int tid = threadIdx.x;
    int w = tid >> 6, lane = tid & 63;
    int g = w >> 1;
    int h = w & 1;
    int o0 = __builtin_amdgcn_readfirstlane(h << 4);
    int nl = g * 64 + lane;
    int idx = blockIdx.x * 128 + nl;
    unsigned int* Sc = bufS + nl * 20;
    unsigned int* Tc = bufT + nl * 20;
    unsigned int* Cc = bufC + nl * 36;

    const float* v = vert + (size_t)idx * 11;
    float qk0 = v[0], qk1 = v[1], qk2 = v[2];
    float q00 = v[3], q01 = v[4], q02 = v[5];
    float qg0 = v[6], qg1 = v[7], qg2 = v[8];
    float col0 = v[9], col1 = v[10];

    for (int cfh = 0; cfh < 2; ++cfh) {
        float a0 = cfh ? qg0 : q00;
        float a1 = cfh ? qg1 : q01;
        float a2 = cfh ? qg2 : q02;
        if (h == 0) {
            #pragma unroll
            for (int i = 0; i < 4; ++i) {
                Sc[i] = pkrtz(
                    lrelu(qk0 * Wx[4 * i]     + a0 * Wx[4 * i + 1] + bx[2 * i]),
                    lrelu(qk0 * Wx[4 * i + 2] + a0 * Wx[4 * i + 3] + bx[2 * i + 1]));
                Sc[4 + i] = pkrtz(
                    lrelu(qk1 * Wy[4 * i]     + a1 * Wy[4 * i + 1] + by[2 * i]),
                    lrelu(qk1 * Wy[4 * i + 2] + a1 * Wy[4 * i + 3] + by[2 * i + 1]));
            }
        } else {
            #pragma unroll
            for (int i = 0; i < 4; ++i) {
                Sc[8 + i] = pkrtz(
                    lrelu(qk2 * Wth[4 * i]     + a2 * Wth[4 * i + 1] + bth[2 * i]),
                    lrelu(qk2 * Wth[4 * i + 2] + a2 * Wth[4 * i + 3] + bth[2 * i + 1]));
            }
        }
        __syncthreads();

        float hh[16];
        #pragma unroll
        for (int o = 0; o < 16; ++o) hh[o] = b1c[o0 + o];
        layerP16(Sc, 3, o0, W1cTp, hh);              // 24 feats = 12 pairs
        #pragma unroll
        for (int q = 0; q < 8; ++q)
            Tc[h * 8 + q] = pkrtz(lrelu(hh[2 * q]), lrelu(hh[2 * q + 1]));
        __syncthreads();

        float gg[16];
        #pragma unroll
        for (int o = 0; o < 16; ++o) gg[o] = b2c[o0 + o];
        layerP16(Tc, 4, o0, W2cTp, gg);              // 32 feats = 16 pairs
        #pragma unroll
        for (int q = 0; q < 8; ++q)
            Cc[cfh * 16 + h * 8 + q] = pkrtz(lrelu(gg[2 * q]), lrelu(gg[2 * q + 1]));
        __syncthreads();
    }

    float v1[16];
    #pragma unroll
    for (int o = 0; o < 16; ++o) v1[o] = b1v[o0 + o];
    layerP16(Cc, 8, o0, W1vTp, v1);                  // 64 feats = 32 pairs
    #pragma unroll
    for (int q = 0; q < 8; ++q)
        Sc[h * 8 + q] = pkrtz(lrelu(v1[2 * q]), lrelu(v1[2 * q + 1]));
    __syncthreads();

    float v2[16];
    #pragma unroll
    for (int o = 0; o < 16; ++o) v2[o] = b2v[o0 + o];
    layerP16(Sc, 4, o0, W2vTp, v2);                  // 32 feats = 16 pairs
    #pragma unroll
    for (int q = 0; q < 8; ++q)
        Tc[h * 8 + q] = pkrtz(lrelu(v2[2 * q]), lrelu(v2[2 * q + 1]));
    __syncthreads();

    float as[16], ad[16];
    #pragma unroll
    for (int o = 0; o < 16; ++o) { as[o] = 0.f; ad[o] = b1e[o0 + o]; }
    layer2P16(Tc, 4, o0, W1sTp, W1dTp, as, ad);      // vfr feats 0..31
    unsigned int colp = pkrtz(col0, col1);           // feats 32,33 = pair-row 16
    #pragma unroll
    for (int o = 0; o < 16; ++o) {
        as[o] = dot2(colp, W1sTp[512 + o0 + o], as[o]);
        ad[o] = dot2(colp, W1dTp[512 + o0 + o], ad[o]);
    }

    unsigned int* ps = asrc + ((size_t)idx << 4) + h * 8;
    unsigned int* pd = adst + ((size_t)idx << 4) + h * 8;
    #pragma unroll
    for (int q = 0; q < 8; ++q) {
        ps[q] = pkrtz(as[2 * q], as[2 * q + 1]);     // f16 pairs
        pd[q] = pkrtz(ad[2 * q], ad[2 * q + 1]);
    }
}

// ---- one 16-edge chunk step (f16 packed datapath) ----
__device__ __forceinline__ void chunk_step(
    const uint4* __restrict__ abq, const int* __restrict__ elist,
    int e0, int end, int e1, int col, int grp,
    uint4& su_c, int& src_n, const uint4& adr,
    const UH8& Bf0, const UH8& Bf1, float bias0, float bias1,
    float& s0, float& s1)
{
    // prefetch next chunk's gather (L2) + next-next elist
    uint4 su_n = abq[(src_n << 2) | grp];
    int src_n2 = elist[imin(e0 + 32 + col, e1)];

    UH8 A;                                           // relu(asrc+adst): 8 packed instr
    A.u[0] = pk_addrelu(su_c.x, adr.x);
    A.u[1] = pk_addrelu(su_c.y, adr.y);
    A.u[2] = pk_addrelu(su_c.z, adr.z);
    A.u[3] = pk_addrelu(su_c.w, adr.w);
    if ((e0 + col) >= end) {                         // zero invalid lane's A row
        A.u[0] = 0; A.u[1] = 0; A.u[2] = 0; A.u[3] = 0;
    }

    f32x4 acc0 = {bias0, bias0, bias0, bias0};
    f32x4 acc1 = {bias1, bias1, bias1, bias1};
    acc0 = __builtin_amdgcn_mfma_f32_16x16x32_f16(A.v, Bf0.v, acc0, 0, 0, 0);
    acc1 = __builtin_amdgcn_mfma_f32_16x16x32_f16(A.v, Bf1.v, acc1, 0, 0, 0);

    #pragma unroll
    for (int r = 0; r < 4; ++r) {
        s0 += lrelu(acc0[r]);
        s1 += lrelu(acc1[r]);
    }
    su_c = su_n;
    src_n = src_n2;
}

// ---------------- edge phase: L2 gathers, 512-thr blocks, two interleaved dst
//                  streams, MFMA-batched node-MLP epilogue (16 dsts/wave) ----------------
__global__ __launch_bounds__(512) void edge_kernel(
    const unsigned int* __restrict__ asrc, const unsigned int* __restrict__ adst,
    const int* __restrict__ elist, const int* __restrict__ offs,
    const unsigned short* __restrict__ W2eh, const float* __restrict__ b2e,
    const unsigned short* __restrict__ W1oTh, const float* __restrict__ b1o,
    const float* __restrict__ W2o,  const float* __restrict__ b2o,
    float* __restrict__ fv)
{
    __shared__ unsigned int aggbuf[8 * 16 * 20];    // 10 KB: 8 waves x 16 dsts x 80B rows
    int logical = (blockIdx.x & 7) * 64 + (blockIdx.x >> 3);   // XCD swizzle
    int b = logical >> 4;                           // batch
    int seg = logical & 15;                         // dst segment (128 dsts)
    int tid = threadIdx.x;
    int wv = tid >> 6;                              // 0..7
    int lane = tid & 63;
    int col = lane & 15;
    int grp = lane >> 4;

    const uint4* abq = (const uint4*)(asrc + (((size_t)b * NN) << 4));
    unsigned int* wvagg = aggbuf + wv * (16 * 20);

    UH8 Bf0, Bf1;
    Bf0.q = *(const uint4*)(W2eh + col * 32 + grp * 8);
    Bf1.q = *(const uint4*)(W2eh + (col + 16) * 32 + grp * 8);
    UH8 Bo0, Bo1;                                   // node-MLP B fragments
    Bo0.q = *(const uint4*)(W1oTh + col * 32 + grp * 8);
    Bo1.q = *(const uint4*)(W1oTh + (col + 16) * 32 + grp * 8);
    float bias0 = b2e[col];
    float bias1 = b2e[col + 16];
    float lb0 = lrelu(bias0);
    float lb1 = lrelu(bias1);
    float b1o_lo = b1o[col];
    float b1o_hi = b1o[col + 16];
    float w2o_lo = W2o[col];
    float w2o_hi = W2o[col + 16];
    float b2oc = b2o[0];
    const unsigned int* adb = adst + (((size_t)b * NN) << 4) + grp * 4;

    int dbase = seg * 128 + wv * 16;                // 16 dsts = 8 pairs per wave
    for (int dp = 0; dp < 8; ++dp) {
        int dA = dbase + 2 * dp;
        int dB = dA + 1;
        int startA = offs[dA];
        int endA = offs[dB];
        int endB = offs[dB + 1];
        int startB = endA;
        int degA = endA - startA;
        int degB = endB - startB;
        int e1A = imax(endA - 1, 0);
        int e1B = imax(endB - 1, 0);

        const uint4 adrA = *(const uint4*)(adb + ((size_t)dA << 4));   // f16 packed
        const uint4 adrB = *(const uint4*)(adb + ((size_t)dB << 4));

        int n = imax((degA + 15) >> 4, (degB + 15) >> 4);

        float s0A = 0.f, s1A = 0.f, s0B = 0.f, s1B = 0.f;
        if (n > 0) {
            int srcA = elist[imin(startA + col, e1A)];
            int srcB = elist[imin(startB + col, e1B)];
            uint4 suA = abq[(srcA << 2) | grp];
            uint4 suB = abq[(srcB << 2) | grp];
            int srcnA = elist[imin(startA + 16 + col, e1A)];
            int srcnB = elist[imin(startB + 16 + col, e1B)];

            for (int it = 0; it < n; ++it) {
                int e0A = startA + (it << 4);
                int e0B = startB + (it << 4);
                chunk_step(abq, elist, e0A, endA, e1A, col, grp,
                           suA, srcnA, adrA, Bf0, Bf1, bias0, bias1, s0A, s1A);
                chunk_step(abq, elist, e0B, endB, e1B, col, grp,
                           suB, srcnB, adrB, Bf0, Bf1, bias0, bias1, s0B, s1B);
            }
        }

        s0A += __shfl_xor(s0A, 16); s0A += __shfl_xor(s0A, 32);
        s1A += __shfl_xor(s1A, 16); s1A += __shfl_xor(s1A, 32);
        s0B += __shfl_xor(s0B, 16); s0B += __shfl_xor(s0B, 32);
        s1B += __shfl_xor(s1B, 16); s1B += __shfl_xor(s1B, 32);

        float padA = (float)(16 * n - degA);
        float padB = (float)(16 * n - degB);
        s0A -= padA * lb0; s1A -= padA * lb1;
        s0B -= padB * lb0; s1B -= padB * lb1;

        float invA = 1.f / fmaxf((float)degA, 1.f);
        float invB = 1.f / fmaxf((float)degB, 1.f);
        // write agg rows (f16, feature-interleaved k': 2m=feat m, 2m+1=feat 16+m)
        if (grp == 0) {
            wvagg[(2 * dp) * 20 + col]     = pkrtz(s0A * invA, s1A * invA);
            wvagg[(2 * dp + 1) * 20 + col] = pkrtz(s0B * invB, s1B * invB);
        }
    }

    // ---- batched node MLP for the wave's 16 dsts (one A-frag read + 2 MFMAs)
    UH8 Ao;
    Ao.q = *(const uint4*)(wvagg + col * 20 + grp * 4);   // row=col(dst), k'=grp*8..+7
    f32x4 acc0 = {b1o_lo, b1o_lo, b1o_lo, b1o_lo};        // f1[dst][o=col]
    f32x4 acc1 = {b1o_hi, b1o_hi, b1o_hi, b1o_hi};        // f1[dst][o=col+16]
    acc0 = __builtin_amdgcn_mfma_f32_16x16x32_f16(Ao.v, Bo0.v, acc0, 0, 0, 0);
    acc1 = __builtin_amdgcn_mfma_f32_16x16x32_f16(Ao.v, Bo1.v, acc1, 0, 0, 0);

    float* fvb = fv + (size_t)b * NN + dbase + grp * 4;
    #pragma unroll
    for (int r = 0; r < 4; ++r) {                          // dst = dbase + grp*4 + r
        float t = fmaxf(acc0[r], 0.f) * w2o_lo + fmaxf(acc1[r], 0.f) * w2o_hi;
        t += __shfl_xor(t, 1);
        t += __shfl_xor(t, 2);
        t += __shfl_xor(t, 4);
        t += __shfl_xor(t, 8);
        if (col == 0) fvb[r] = lrelu(t + b2oc);
    }
}

// ---------------- final: out[b] = sigmoid(dot(fv[b,:], Wg) + bg) ----------------
__global__ __launch_bounds__(256) void final_kernel(
    const float* __restrict__ fv, const float* __restrict__ Wg,
    const float* __restrict__ bg, float* __restrict__ out)
{
    int b = blockIdx.x;
    int t = threadIdx.x;
    float p = 0.f;
    for (int n = t; n < NN; n += 256) p += fv[(size_t)b * NN + n] * Wg[n];
    __shared__ float red[256];
    red[t] = p;
    __syncthreads();
    for (int s = 128; s > 0; s >>= 1) {
        if (t < s) red[t] += red[t + s];
        __syncthreads();
    }
    if (t == 0) {
        float x = red[0] + bg[0];
        out[b] = 1.f / (1.f + expf(-x));
    }
}

extern "C" void kernel_launch(void* const* d_in, const int* in_sizes, int n_in,
                              void* d_out, int out_size, void* d_ws, size_t ws_size,
                              hipStream_t stream)
{
    const float* vert = (const float*)d_in[0];
    const int*   edges = (const int*)d_in[1];
    const float* Wx  = (const float*)d_in[2];
    const float* bx  = (const float*)d_in[3];
    const float* Wy  = (const float*)d_in[4];
    const float* by  = (const float*)d_in[5];
    const float* Wth = (const float*)d_in[6];
    const float* bth = (const float*)d_in[7];
    const float* W1c = (const float*)d_in[8];
    const float* b1c = (const float*)d_in[9];
    const float* W2c = (const float*)d_in[10];
    const float* b2c = (const float*)d_in[11];
    const float* W1v = (const float*)d_in[12];
    const float* b1v = (const float*)d_in[13];
    const float* W2v = (const float*)d_in[14];
    const float* b2v = (const float*)d_in[15];
    const float* W1e = (const float*)d_in[16];
    const float* b1e = (const float*)d_in[17];
    const float* W2e = (const float*)d_in[18];
    const float* b2e = (const float*)d_in[19];
    const float* W1o = (const float*)d_in[20];
    const float* b1o = (const float*)d_in[21];
    const float* W2o = (const float*)d_in[22];
    const float* b2o = (const float*)d_in[23];
    const float* Wg  = (const float*)d_in[24];
    const float* bg  = (const float*)d_in[25];
    float* out = (float*)d_out;

    // workspace layout (~9 MB, all chunks 16B-aligned)
    char* w = (char*)d_ws;
    unsigned int* asrc = (unsigned int*)w; w += (size_t)B * NN * 32 * 2;  // f16 pairs
    unsigned int* adst = (unsigned int*)w; w += (size_t)B * NN * 32 * 2;
    float* fv   = (float*)w; w += (size_t)B * NN * 4;
    unsigned int* W1cTp = (unsigned int*)w; w += 12 * 32 * 4;
    unsigned int* W2cTp = (unsigned int*)w; w += 16 * 32 * 4;
    unsigned int* W1vTp = (unsigned int*)w; w += 32 * 32 * 4;
    unsigned int* W2vTp = (unsigned int*)w; w += 16 * 32 * 4;
    unsigned int* W1sTp = (unsigned int*)w; w += 17 * 32 * 4;
    unsigned int* W1dTp = (unsigned int*)w; w += 17 * 32 * 4;
    unsigned short* W2eh  = (unsigned short*)w; w += 32 * 32 * 2;
    unsigned short* W1oTh = (unsigned short*)w; w += 32 * 32 * 2;
    int* cnt    = (int*)w;   w += NN * 4;
    int* cursor = (int*)w;   w += NN * 4;
    int* offs   = (int*)w;   w += 2052 * 4;
    int* elist  = (int*)w;   w += E * 4;

    prep_zero_kernel<<<12, 256, 0, stream>>>(W1c, W2c, W1v, W2v, W1e, W2e, W1o,
                                             W1cTp, W2cTp, W1vTp, W2vTp, W1sTp, W1dTp,
                                             W2eh, W1oTh, cnt, cursor);
    count_kernel<<<E / 256, 256, 0, stream>>>(edges, cnt);
    scan_kernel<<<1, 1024, 0, stream>>>(cnt, offs);
    fill_kernel<<<E / 256, 256, 0, stream>>>(edges, offs, cursor, elist);

    vertex_kernel<<<(B * NN) / 128, 256, 0, stream>>>(
        vert, Wx, bx, Wy, by, Wth, bth, b1c, b2c, b1v, b2v, b1e,
        W1cTp, W2cTp, W1vTp, W2vTp, W1sTp, W1dTp, asrc, adst);

    edge_kernel<<<B * 16, 512, 0, stream>>>(
        asrc, adst, elist, offs, W2eh, b2e, W1oTh, b1o, W2o, b2o, fv);

    final_kernel<<<B, 256, 0, stream>>>(fv, Wg, bg, out);
}

// Round 24
// 90.227 us; speedup vs baseline: 1.3797x; 1.0232x over previous
//
#include <hip/hip_runtime.h>
#include <hip/hip_fp16.h>
#include <math.h>

constexpr int B = 32;
constexpr int NN = 2048;   // nodes
constexpr int E = 65536;   // edges
constexpr float SLOPE = 0.01f;

typedef __attribute__((ext_vector_type(8))) _Float16 f16x8;
typedef __attribute__((ext_vector_type(2))) _Float16 f16x2;
typedef __attribute__((ext_vector_type(4))) float f32x4;

__device__ __forceinline__ float lrelu(float x) { return fmaxf(x, SLOPE * x); }
__device__ __forceinline__ int imin(int a, int b) { return a < b ? a : b; }
__device__ __forceinline__ int imax(int a, int b) { return a > b ? a : b; }

// f16 pair pack (RTZ), single instruction
__device__ __forceinline__ unsigned int pkrtz(float lo, float hi) {
    unsigned int r;
    asm("v_cvt_pkrtz_f16_f32 %0, %1, %2" : "=v"(r) : "v"(lo), "v"(hi));
    return r;
}
// packed f16: max(a+b, 0) in 2 instructions
__device__ __forceinline__ unsigned int pk_addrelu(unsigned int a, unsigned int b) {
    unsigned int s, r;
    asm("v_pk_add_f16 %0, %1, %2" : "=v"(s) : "v"(a), "v"(b));
    asm("v_pk_max_f16 %0, %1, %2" : "=v"(r) : "v"(s), "v"(0u));
    return r;
}
// f16 pair RNE pack (prep, precision)
__device__ __forceinline__ unsigned int pkh2(float lo, float hi) {
    return (unsigned int)__half_as_ushort(__float2half(lo)) |
           ((unsigned int)__half_as_ushort(__float2half(hi)) << 16);
}

// 2xf16 dot with f32 accumulate: one VOP3P instr where available
__device__ __forceinline__ float dot2(unsigned int x, unsigned int w, float c) {
#if __has_builtin(__builtin_amdgcn_fdot2)
    union Uh { unsigned int u; f16x2 h; };
    Uh a; a.u = x;
    Uh b; b.u = w;
    return __builtin_amdgcn_fdot2(a.h, b.h, c, false);
#else
    float xl = __half2float(__ushort_as_half((unsigned short)(x & 0xffffu)));
    float xh = __half2float(__ushort_as_half((unsigned short)(x >> 16)));
    float wl = __half2float(__ushort_as_half((unsigned short)(w & 0xffffu)));
    float wh = __half2float(__ushort_as_half((unsigned short)(w >> 16)));
    return c + xl * wl + xh * wh;
#endif
}

union UH8 { unsigned int u[4]; uint4 q; f16x8 v; };

// ---- pair-packed layer helpers (vertex; o0 wave-uniform SGPR) ----
__device__ __forceinline__ void layerP16(const unsigned int* col, int G, int o0,
                                         const unsigned int* __restrict__ Wp,
                                         float acc[16]) {
    uint4 cur = *(const uint4*)col;
    #pragma unroll 1
    for (int jj = 0; jj < G; ++jj) {
        uint4 nxt = (jj + 1 < G) ? *(const uint4*)(col + (jj + 1) * 4) : cur;
        const unsigned int* Wq = Wp + jj * 128 + o0;
        #pragma unroll
        for (int o = 0; o < 16; ++o) acc[o] = dot2(cur.x, Wq[o], acc[o]);
        #pragma unroll
        for (int o = 0; o < 16; ++o) acc[o] = dot2(cur.y, Wq[32 + o], acc[o]);
        #pragma unroll
        for (int o = 0; o < 16; ++o) acc[o] = dot2(cur.z, Wq[64 + o], acc[o]);
        #pragma unroll
        for (int o = 0; o < 16; ++o) acc[o] = dot2(cur.w, Wq[96 + o], acc[o]);
        cur = nxt;
    }
}

__device__ __forceinline__ void layer2P16(const unsigned int* col, int G, int o0,
                                          const unsigned int* __restrict__ Ws,
                                          const unsigned int* __restrict__ Wd,
                                          float a1[16], float a2[16]) {
    uint4 cur = *(const uint4*)col;
    #pragma unroll 1
    for (int jj = 0; jj < G; ++jj) {
        uint4 nxt = (jj + 1 < G) ? *(const uint4*)(col + (jj + 1) * 4) : cur;
        const unsigned int* Wqs = Ws + jj * 128 + o0;
        const unsigned int* Wqd = Wd + jj * 128 + o0;
        #pragma unroll
        for (int o = 0; o < 16; ++o) a1[o] = dot2(cur.x, Wqs[o], a1[o]);
        #pragma unroll
        for (int o = 0; o < 16; ++o) a2[o] = dot2(cur.x, Wqd[o], a2[o]);
        #pragma unroll
        for (int o = 0; o < 16; ++o) a1[o] = dot2(cur.y, Wqs[32 + o], a1[o]);
        #pragma unroll
        for (int o = 0; o < 16; ++o) a2[o] = dot2(cur.y, Wqd[32 + o], a2[o]);
        #pragma unroll
        for (int o = 0; o < 16; ++o) a1[o] = dot2(cur.z, Wqs[64 + o], a1[o]);
        #pragma unroll
        for (int o = 0; o < 16; ++o) a2[o] = dot2(cur.z, Wqd[64 + o], a2[o]);
        #pragma unroll
        for (int o = 0; o < 16; ++o) a1[o] = dot2(cur.w, Wqs[96 + o], a1[o]);
        #pragma unroll
        for (int o = 0; o < 16; ++o) a2[o] = dot2(cur.w, Wqd[96 + o], a2[o]);
        cur = nxt;
    }
}

// ---------------- prep (blocks 8..11) + CSR-counter zero (blocks 0..7) ----------------
__global__ __launch_bounds__(256) void prep_zero_kernel(
    const float* __restrict__ W1c, const float* __restrict__ W2c,
    const float* __restrict__ W1v, const float* __restrict__ W2v,
    const float* __restrict__ W1e, const float* __restrict__ W2e,
    const float* __restrict__ W1o,
    unsigned int* __restrict__ W1cTp, unsigned int* __restrict__ W2cTp,
    unsigned int* __restrict__ W1vTp, unsigned int* __restrict__ W2vTp,
    unsigned int* __restrict__ W1sTp, unsigned int* __restrict__ W1dTp,
    unsigned short* __restrict__ W2eh, unsigned short* __restrict__ W1oTh,
    int* __restrict__ cnt, int* __restrict__ cursor)
{
    int blk = blockIdx.x;
    if (blk < 8) {
        int i = blk * 256 + threadIdx.x;
        cnt[i] = 0;
        cursor[i] = 0;
        return;
    }
    int t = (blk - 8) * 256 + threadIdx.x;         // 0..1023
    for (int i = t; i < 12 * 32; i += 1024) {       // W1c: [32][24]
        int jp = i >> 5, o = i & 31;
        W1cTp[i] = pkh2(W1c[o * 24 + 2 * jp], W1c[o * 24 + 2 * jp + 1]);
    }
    for (int i = t; i < 16 * 32; i += 1024) {       // W2c: [32][32]
        int jp = i >> 5, o = i & 31;
        W2cTp[i] = pkh2(W2c[o * 32 + 2 * jp], W2c[o * 32 + 2 * jp + 1]);
    }
    for (int i = t; i < 32 * 32; i += 1024) {       // W1v: [32][64]
        int jp = i >> 5, o = i & 31;
        W1vTp[i] = pkh2(W1v[o * 64 + 2 * jp], W1v[o * 64 + 2 * jp + 1]);
    }
    for (int i = t; i < 16 * 32; i += 1024) {       // W2v: [32][32]
        int jp = i >> 5, o = i & 31;
        W2vTp[i] = pkh2(W2v[o * 32 + 2 * jp], W2v[o * 32 + 2 * jp + 1]);
    }
    for (int i = t; i < 17 * 32; i += 1024) {       // W1e src half: [32][68] j<34
        int jp = i >> 5, o = i & 31;
        W1sTp[i] = pkh2(W1e[o * 68 + 2 * jp], W1e[o * 68 + 2 * jp + 1]);
    }
    for (int i = t; i < 17 * 32; i += 1024) {       // W1e dst half: j>=34
        int jp = i >> 5, o = i & 31;
        W1dTp[i] = pkh2(W1e[o * 68 + 34 + 2 * jp], W1e[o * 68 + 34 + 2 * jp + 1]);
    }
    for (int i = t; i < 32 * 32; i += 1024) {       // W2e row-major f32 -> f16
        W2eh[i] = __half_as_ushort(__float2half(W2e[i]));
    }
    for (int i = t; i < 512; i += 1024) {
        int o = i >> 4, m = i & 15;
        W1oTh[o * 32 + 2 * m]     = __half_as_ushort(__float2half(W1o[o * 32 + m]));
        W1oTh[o * 32 + 2 * m + 1] = __half_as_ushort(__float2half(W1o[o * 32 + 16 + m]));
    }
}

// ---------------- CSR build ----------------
__global__ __launch_bounds__(256) void count_kernel(const int* __restrict__ edges, int* __restrict__ cnt)
{
    int e = blockIdx.x * 256 + threadIdx.x;
    if (e < E) atomicAdd(&cnt[edges[E + e]], 1);
}

__global__ __launch_bounds__(1024) void scan_kernel(const int* __restrict__ cnt, int* __restrict__ offs)
{
    __shared__ int s[1024];
    int t = threadIdx.x;
    int c0 = cnt[2 * t], c1 = cnt[2 * t + 1];
    int own = c0 + c1;
    s[t] = own;
    __syncthreads();
    int v = own;
    for (int d = 1; d < 1024; d <<= 1) {
        int add = (t >= d) ? s[t - d] : 0;
        __syncthreads();
        v += add;
        s[t] = v;
        __syncthreads();
    }
    int excl = v - own;
    offs[2 * t] = excl;
    offs[2 * t + 1] = excl + c0;
    if (t == 1023) offs[2048] = v;
}

__global__ __launch_bounds__(256) void fill_kernel(
    const int* __restrict__ edges, const int* __restrict__ offs,
    int* __restrict__ cursor, int* __restrict__ elist)
{
    int e = blockIdx.x * 256 + threadIdx.x;
    if (e < E) {
        int d = edges[E + e];
        int p = atomicAdd(&cursor[d], 1);
        elist[offs[d] + p] = edges[e];
    }
}

// ---------------- vertex MLP: 2 threads/node, wave-split halves,
//                  f16 pair activations + v_dot2_f32_f16 layers ----------------
__global__ __launch_bounds__(256) void vertex_kernel(
    const float* __restrict__ vert,
    const float* __restrict__ Wx,  const float* __restrict__ bx,
    const float* __restrict__ Wy,  const float* __restrict__ by,
    const float* __restrict__ Wth, const float* __restrict__ bth,
    const float* __restrict__ b1c, const float* __restrict__ b2c,
    const float* __restrict__ b1v, const float* __restrict__ b2v,
    const float* __restrict__ b1e,
    const unsigned int* __restrict__ W1cTp, const unsigned int* __restrict__ W2cTp,
    const unsigned int* __restrict__ W1vTp, const unsigned int* __restrict__ W2vTp,
    const unsigned int* __restrict__ W1sTp, const unsigned int* __restrict__ W1dTp,
    unsigned int* __restrict__ asrc, unsigned int* __restrict__ adst)
{
    __shared__ unsigned int bufS[128 * 20];   // 10 KB, stride 80 B (16 pairs used)
    __shared__ unsigned int bufT[128 * 20];   // 10 KB
    __shared__ unsigned int bufC[128 * 36];   // 18 KB, stride 144 B (32 pairs used)
    int tid = threadIdx.x;
    int w = tid >> 6, lane = tid & 63;
    int g = w >> 1;
    int h = w & 1;
    int o0 = __builtin_amdgcn_readfirstlane(h << 4);
    int nl = g * 64 + lane;
    int idx = blockIdx.x * 128 + nl;
    unsigned int* Sc = bufS + nl * 20;
    unsigned int* Tc = bufT + nl * 20;
    unsigned int* Cc = bufC + nl * 36;

    const float* v = vert + (size_t)idx * 11;
    float qk0 = v[0], qk1 = v[1], qk2 = v[2];
    float q00 = v[3], q01 = v[4], q02 = v[5];
    float qg0 = v[6], qg1 = v[7], qg2 = v[8];
    float col0 = v[9], col1 = v[10];

    for (int cfh = 0; cfh < 2; ++cfh) {
        float a0 = cfh ? qg0 : q00;
        float a1 = cfh ? qg1 : q01;
        float a2 = cfh ? qg2 : q02;
        if (h == 0) {
            #pragma unroll
            for (int i = 0; i < 4; ++i) {
                Sc[i] = pkrtz(
                    lrelu(qk0 * Wx[4 * i]     + a0 * Wx[4 * i + 1] + bx[2 * i]),
                    lrelu(qk0 * Wx[4 * i + 2] + a0 * Wx[4 * i + 3] + bx[2 * i + 1]));
                Sc[4 + i] = pkrtz(
                    lrelu(qk1 * Wy[4 * i]     + a1 * Wy[4 * i + 1] + by[2 * i]),
                    lrelu(qk1 * Wy[4 * i + 2] + a1 * Wy[4 * i + 3] + by[2 * i + 1]));
            }
        } else {
            #pragma unroll
            for (int i = 0; i < 4; ++i) {
                Sc[8 + i] = pkrtz(
                    lrelu(qk2 * Wth[4 * i]     + a2 * Wth[4 * i + 1] + bth[2 * i]),
                    lrelu(qk2 * Wth[4 * i + 2] + a2 * Wth[4 * i + 3] + bth[2 * i + 1]));
            }
        }
        __syncthreads();

        float hh[16];
        #pragma unroll
        for (int o = 0; o < 16; ++o) hh[o] = b1c[o0 + o];
        layerP16(Sc, 3, o0, W1cTp, hh);              // 24 feats = 12 pairs
        #pragma unroll
        for (int q = 0; q < 8; ++q)
            Tc[h * 8 + q] = pkrtz(lrelu(hh[2 * q]), lrelu(hh[2 * q + 1]));
        __syncthreads();

        float gg[16];
        #pragma unroll
        for (int o = 0; o < 16; ++o) gg[o] = b2c[o0 + o];
        layerP16(Tc, 4, o0, W2cTp, gg);              // 32 feats = 16 pairs
        #pragma unroll
        for (int q = 0; q < 8; ++q)
            Cc[cfh * 16 + h * 8 + q] = pkrtz(lrelu(gg[2 * q]), lrelu(gg[2 * q + 1]));
        __syncthreads();
    }

    float v1[16];
    #pragma unroll
    for (int o = 0; o < 16; ++o) v1[o] = b1v[o0 + o];
    layerP16(Cc, 8, o0, W1vTp, v1);                  // 64 feats = 32 pairs
    #pragma unroll
    for (int q = 0; q < 8; ++q)
        Sc[h * 8 + q] = pkrtz(lrelu(v1[2 * q]), lrelu(v1[2 * q + 1]));
    __syncthreads();

    float v2[16];
    #pragma unroll
    for (int o = 0; o < 16; ++o) v2[o] = b2v[o0 + o];
    layerP16(Sc, 4, o0, W2vTp, v2);                  // 32 feats = 16 pairs
    #pragma unroll
    for (int q = 0; q < 8; ++q)
        Tc[h * 8 + q] = pkrtz(lrelu(v2[2 * q]), lrelu(v2[2 * q + 1]));
    __syncthreads();

    float as[16], ad[16];
    #pragma unroll
    for (int o = 0; o < 16; ++o) { as[o] = 0.f; ad[o] = b1e[o0 + o]; }
    layer2P16(Tc, 4, o0, W1sTp, W1dTp, as, ad);      // vfr feats 0..31
    unsigned int colp = pkrtz(col0, col1);           // feats 32,33 = pair-row 16
    #pragma unroll
    for (int o = 0; o < 16; ++o) {
        as[o] = dot2(colp, W1sTp[512 + o0 + o], as[o]);
        ad[o] = dot2(colp, W1dTp[512 + o0 + o], ad[o]);
    }

    unsigned int* ps = asrc + ((size_t)idx << 4) + h * 8;
    unsigned int* pd = adst + ((size_t)idx << 4) + h * 8;
    #pragma unroll
    for (int q = 0; q < 8; ++q) {
        ps[q] = pkrtz(as[2 * q], as[2 * q + 1]);     // f16 pairs
        pd[q] = pkrtz(ad[2 * q], ad[2 * q + 1]);
    }
}

// ---- one 16-edge chunk step (f16 packed datapath) ----
__device__ __forceinline__ void chunk_step(
    const uint4* __restrict__ abq, const int* __restrict__ elist,
    int e0, int end, int e1, int col, int grp,
    uint4& su_c, int& src_n, const uint4& adr,
    const UH8& Bf0, const UH8& Bf1, float bias0, float bias1,
    float& s0, float& s1)
{
    // prefetch next chunk's gather (L2) + next-next elist
    uint4 su_n = abq[(src_n << 2) | grp];
    int src_n2 = elist[imin(e0 + 32 + col, e1)];

    UH8 A;                                           // relu(asrc+adst): 8 packed instr
    A.u[0] = pk_addrelu(su_c.x, adr.x);
    A.u[1] = pk_addrelu(su_c.y, adr.y);
    A.u[2] = pk_addrelu(su_c.z, adr.z);
    A.u[3] = pk_addrelu(su_c.w, adr.w);
    if ((e0 + col) >= end) {                         // zero invalid lane's A row
        A.u[0] = 0; A.u[1] = 0; A.u[2] = 0; A.u[3] = 0;
    }

    f32x4 acc0 = {bias0, bias0, bias0, bias0};
    f32x4 acc1 = {bias1, bias1, bias1, bias1};
    acc0 = __builtin_amdgcn_mfma_f32_16x16x32_f16(A.v, Bf0.v, acc0, 0, 0, 0);
    acc1 = __builtin_amdgcn_mfma_f32_16x16x32_f16(A.v, Bf1.v, acc1, 0, 0, 0);

    #pragma unroll
    for (int r = 0; r < 4; ++r) {
        s0 += lrelu(acc0[r]);
        s1 += lrelu(acc1[r]);
    }
    su_c = su_n;
    src_n = src_n2;
}

// ---------------- edge phase: L2 gathers, 512-thr blocks, FOUR interleaved dst
//                  streams, MFMA-batched node-MLP epilogue (16 dsts/wave) ----------------
__global__ __launch_bounds__(512) void edge_kernel(
    const unsigned int* __restrict__ asrc, const unsigned int* __restrict__ adst,
    const int* __restrict__ elist, const int* __restrict__ offs,
    const unsigned short* __restrict__ W2eh, const float* __restrict__ b2e,
    const unsigned short* __restrict__ W1oTh, const float* __restrict__ b1o,
    const float* __restrict__ W2o,  const float* __restrict__ b2o,
    float* __restrict__ fv)
{
    __shared__ unsigned int aggbuf[8 * 16 * 20];    // 10 KB: 8 waves x 16 dsts x 80B rows
    int logical = (blockIdx.x & 7) * 64 + (blockIdx.x >> 3);   // XCD swizzle
    int b = logical >> 4;                           // batch
    int seg = logical & 15;                         // dst segment (128 dsts)
    int tid = threadIdx.x;
    int wv = tid >> 6;                              // 0..7
    int lane = tid & 63;
    int col = lane & 15;
    int grp = lane >> 4;

    const uint4* abq = (const uint4*)(asrc + (((size_t)b * NN) << 4));
    unsigned int* wvagg = aggbuf + wv * (16 * 20);

    UH8 Bf0, Bf1;
    Bf0.q = *(const uint4*)(W2eh + col * 32 + grp * 8);
    Bf1.q = *(const uint4*)(W2eh + (col + 16) * 32 + grp * 8);
    UH8 Bo0, Bo1;                                   // node-MLP B fragments
    Bo0.q = *(const uint4*)(W1oTh + col * 32 + grp * 8);
    Bo1.q = *(const uint4*)(W1oTh + (col + 16) * 32 + grp * 8);
    float bias0 = b2e[col];
    float bias1 = b2e[col + 16];
    float lb0 = lrelu(bias0);
    float lb1 = lrelu(bias1);
    float b1o_lo = b1o[col];
    float b1o_hi = b1o[col + 16];
    float w2o_lo = W2o[col];
    float w2o_hi = W2o[col + 16];
    float b2oc = b2o[0];
    const unsigned int* adb = adst + (((size_t)b * NN) << 4) + grp * 4;

    int dbase = seg * 128 + wv * 16;                // 16 dsts = 4 quads per wave
    for (int dp = 0; dp < 4; ++dp) {
        int dA = dbase + 4 * dp;
        int oA = offs[dA];
        int oB = offs[dA + 1];
        int oC = offs[dA + 2];
        int oD = offs[dA + 3];
        int oE = offs[dA + 4];
        int degA = oB - oA, degB = oC - oB, degC = oD - oC, degD = oE - oD;
        int e1A = imax(oB - 1, 0), e1B = imax(oC - 1, 0);
        int e1C = imax(oD - 1, 0), e1D = imax(oE - 1, 0);

        const uint4 adrA = *(const uint4*)(adb + ((size_t)dA << 4));
        const uint4 adrB = *(const uint4*)(adb + ((size_t)(dA + 1) << 4));
        const uint4 adrC = *(const uint4*)(adb + ((size_t)(dA + 2) << 4));
        const uint4 adrD = *(const uint4*)(adb + ((size_t)(dA + 3) << 4));

        int n = imax(imax((degA + 15) >> 4, (degB + 15) >> 4),
                     imax((degC + 15) >> 4, (degD + 15) >> 4));

        float s0A = 0.f, s1A = 0.f, s0B = 0.f, s1B = 0.f;
        float s0C = 0.f, s1C = 0.f, s0D = 0.f, s1D = 0.f;
        if (n > 0) {
            int srcA = elist[imin(oA + col, e1A)];
            int srcB = elist[imin(oB + col, e1B)];
            int srcC = elist[imin(oC + col, e1C)];
            int srcD = elist[imin(oD + col, e1D)];
            uint4 suA = abq[(srcA << 2) | grp];
            uint4 suB = abq[(srcB << 2) | grp];
            uint4 suC = abq[(srcC << 2) | grp];
            uint4 suD = abq[(srcD << 2) | grp];
            int srcnA = elist[imin(oA + 16 + col, e1A)];
            int srcnB = elist[imin(oB + 16 + col, e1B)];
            int srcnC = elist[imin(oC + 16 + col, e1C)];
            int srcnD = elist[imin(oD + 16 + col, e1D)];

            for (int it = 0; it < n; ++it) {
                int sh = it << 4;
                chunk_step(abq, elist, oA + sh, oB, e1A, col, grp,
                           suA, srcnA, adrA, Bf0, Bf1, bias0, bias1, s0A, s1A);
                chunk_step(abq, elist, oB + sh, oC, e1B, col, grp,
                           suB, srcnB, adrB, Bf0, Bf1, bias0, bias1, s0B, s1B);
                chunk_step(abq, elist, oC + sh, oD, e1C, col, grp,
                           suC, srcnC, adrC, Bf0, Bf1, bias0, bias1, s0C, s1C);
                chunk_step(abq, elist, oD + sh, oE, e1D, col, grp,
                           suD, srcnD, adrD, Bf0, Bf1, bias0, bias1, s0D, s1D);
            }
        }

        s0A += __shfl_xor(s0A, 16); s0A += __shfl_xor(s0A, 32);
        s1A += __shfl_xor(s1A, 16); s1A += __shfl_xor(s1A, 32);
        s0B += __shfl_xor(s0B, 16); s0B += __shfl_xor(s0B, 32);
        s1B += __shfl_xor(s1B, 16); s1B += __shfl_xor(s1B, 32);
        s0C += __shfl_xor(s0C, 16); s0C += __shfl_xor(s0C, 32);
        s1C += __shfl_xor(s1C, 16); s1C += __shfl_xor(s1C, 32);
        s0D += __shfl_xor(s0D, 16); s0D += __shfl_xor(s0D, 32);
        s1D += __shfl_xor(s1D, 16); s1D += __shfl_xor(s1D, 32);

        float padA = (float)(16 * n - degA);
        float padB = (float)(16 * n - degB);
        float padC = (float)(16 * n - degC);
        float padD = (float)(16 * n - degD);
        s0A -= padA * lb0; s1A -= padA * lb1;
        s0B -= padB * lb0; s1B -= padB * lb1;
        s0C -= padC * lb0; s1C -= padC * lb1;
        s0D -= padD * lb0; s1D -= padD * lb1;

        float invA = 1.f / fmaxf((float)degA, 1.f);
        float invB = 1.f / fmaxf((float)degB, 1.f);
        float invC = 1.f / fmaxf((float)degC, 1.f);
        float invD = 1.f / fmaxf((float)degD, 1.f);
        if (grp == 0) {
            wvagg[(4 * dp) * 20 + col]     = pkrtz(s0A * invA, s1A * invA);
            wvagg[(4 * dp + 1) * 20 + col] = pkrtz(s0B * invB, s1B * invB);
            wvagg[(4 * dp + 2) * 20 + col] = pkrtz(s0C * invC, s1C * invC);
            wvagg[(4 * dp + 3) * 20 + col] = pkrtz(s0D * invD, s1D * invD);
        }
    }

    // ---- batched node MLP for the wave's 16 dsts (one A-frag read + 2 MFMAs)
    UH8 Ao;
    Ao.q = *(const uint4*)(wvagg + col * 20 + grp * 4);   // row=col(dst), k'=grp*8..+7
    f32x4 acc0 = {b1o_lo, b1o_lo, b1o_lo, b1o_lo};        // f1[dst][o=col]
    f32x4 acc1 = {b1o_hi, b1o_hi, b1o_hi, b1o_hi};        // f1[dst][o=col+16]
    acc0 = __builtin_amdgcn_mfma_f32_16x16x32_f16(Ao.v, Bo0.v, acc0, 0, 0, 0);
    acc1 = __builtin_amdgcn_mfma_f32_16x16x32_f16(Ao.v, Bo1.v, acc1, 0, 0, 0);

    float* fvb = fv + (size_t)b * NN + dbase + grp * 4;
    #pragma unroll
    for (int r = 0; r < 4; ++r) {                          // dst = dbase + grp*4 + r
        float t = fmaxf(acc0[r], 0.f) * w2o_lo + fmaxf(acc1[r], 0.f) * w2o_hi;
        t += __shfl_xor(t, 1);
        t += __shfl_xor(t, 2);
        t += __shfl_xor(t, 4);
        t += __shfl_xor(t, 8);
        if (col == 0) fvb[r] = lrelu(t + b2oc);
    }
}

// ---------------- final: out[b] = sigmoid(dot(fv[b,:], Wg) + bg) ----------------
__global__ __launch_bounds__(256) void final_kernel(
    const float* __restrict__ fv, const float* __restrict__ Wg,
    const float* __restrict__ bg, float* __restrict__ out)
{
    int b = blockIdx.x;
    int t = threadIdx.x;
    float p = 0.f;
    for (int n = t; n < NN; n += 256) p += fv[(size_t)b * NN + n] * Wg[n];
    __shared__ float red[256];
    red[t] = p;
    __syncthreads();
    for (int s = 128; s > 0; s >>= 1) {
        if (t < s) red[t] += red[t + s];
        __syncthreads();
    }
    if (t == 0) {
        float x = red[0] + bg[0];
        out[b] = 1.f / (1.f + expf(-x));
    }
}

extern "C" void kernel_launch(void* const* d_in, const int* in_sizes, int n_in,
                              void* d_out, int out_size, void* d_ws, size_t ws_size,
                              hipStream_t stream)
{
    const float* vert = (const float*)d_in[0];
    const int*   edges = (const int*)d_in[1];
    const float* Wx  = (const float*)d_in[2];
    const float* bx  = (const float*)d_in[3];
    const float* Wy  = (const float*)d_in[4];
    const float* by  = (const float*)d_in[5];
    const float* Wth = (const float*)d_in[6];
    const float* bth = (const float*)d_in[7];
    const float* W1c = (const float*)d_in[8];
    const float* b1c = (const float*)d_in[9];
    const float* W2c = (const float*)d_in[10];
    const float* b2c = (const float*)d_in[11];
    const float* W1v = (const float*)d_in[12];
    const float* b1v = (const float*)d_in[13];
    const float* W2v = (const float*)d_in[14];
    const float* b2v = (const float*)d_in[15];
    const float* W1e = (const float*)d_in[16];
    const float* b1e = (const float*)d_in[17];
    const float* W2e = (const float*)d_in[18];
    const float* b2e = (const float*)d_in[19];
    const float* W1o = (const float*)d_in[20];
    const float* b1o = (const float*)d_in[21];
    const float* W2o = (const float*)d_in[22];
    const float* b2o = (const float*)d_in[23];
    const float* Wg  = (const float*)d_in[24];
    const float* bg  = (const float*)d_in[25];
    float* out = (float*)d_out;

    // workspace layout (~9 MB, all chunks 16B-aligned)
    char* w = (char*)d_ws;
    unsigned int* asrc = (unsigned int*)w; w += (size_t)B * NN * 32 * 2;  // f16 pairs
    unsigned int* adst = (unsigned int*)w; w += (size_t)B * NN * 32 * 2;
    float* fv   = (float*)w; w += (size_t)B * NN * 4;
    unsigned int* W1cTp = (unsigned int*)w; w += 12 * 32 * 4;
    unsigned int* W2cTp = (unsigned int*)w; w += 16 * 32 * 4;
    unsigned int* W1vTp = (unsigned int*)w; w += 32 * 32 * 4;
    unsigned int* W2vTp = (unsigned int*)w; w += 16 * 32 * 4;
    unsigned int* W1sTp = (unsigned int*)w; w += 17 * 32 * 4;
    unsigned int* W1dTp = (unsigned int*)w; w += 17 * 32 * 4;
    unsigned short* W2eh  = (unsigned short*)w; w += 32 * 32 * 2;
    unsigned short* W1oTh = (unsigned short*)w; w += 32 * 32 * 2;
    int* cnt    = (int*)w;   w += NN * 4;
    int* cursor = (int*)w;   w += NN * 4;
    int* offs   = (int*)w;   w += 2052 * 4;
    int* elist  = (int*)w;   w += E * 4;

    prep_zero_kernel<<<12, 256, 0, stream>>>(W1c, W2c, W1v, W2v, W1e, W2e, W1o,
                                             W1cTp, W2cTp, W1vTp, W2vTp, W1sTp, W1dTp,
                                             W2eh, W1oTh, cnt, cursor);
    count_kernel<<<E / 256, 256, 0, stream>>>(edges, cnt);
    scan_kernel<<<1, 1024, 0, stream>>>(cnt, offs);
    fill_kernel<<<E / 256, 256, 0, stream>>>(edges, offs, cursor, elist);

    vertex_kernel<<<(B * NN) / 128, 256, 0, stream>>>(
        vert, Wx, bx, Wy, by, Wth, bth, b1c, b2c, b1v, b2v, b1e,
        W1cTp, W2cTp, W1vTp, W2vTp, W1sTp, W1dTp, asrc, adst);

    edge_kernel<<<B * 16, 512, 0, stream>>>(
        asrc, adst, elist, offs, W2eh, b2e, W1oTh, b1o, W2o, b2o, fv);

    final_kernel<<<B, 256, 0, stream>>>(fv, Wg, bg, out);
}